// Round 6
// baseline (901.671 us; speedup 1.0000x reference)
//
#include <hip/hip_runtime.h>

#define IN_DIM 512
#define NBATCH 8192

// ---- pipelined kernel geometry: 128 rows x 256-col half, 4 waves of 128x64, BK=32 ----
#define PH_BM 128
#define PH_BNT 256
#define PH_BK 32
#define SLOT_U16 8192                     // 16 KB B-slot ([256 col][32 k] bf16)
#define PH_HSTR 260                       // Hsh stride u16 (4-row step = 520 dw % 32 = 8)
#define PH_LDS_BYTES (PH_BM * PH_HSTR * 2)   // 66,560 B (3 slots = 48 KB overlaid at offset 0)

typedef short s16x8 __attribute__((ext_vector_type(8)));
typedef float f32x4 __attribute__((ext_vector_type(4)));

__device__ __forceinline__ unsigned short f2bf(float f) {
    union { float f; unsigned int u; } c;
    c.f = f;
    unsigned int u = c.u;
    u += 0x7fffu + ((u >> 16) & 1u);   // round-to-nearest-even
    return (unsigned short)(u >> 16);
}

__device__ __forceinline__ void gload16(const unsigned short* g, unsigned short* l) {
    __builtin_amdgcn_global_load_lds(
        (const __attribute__((address_space(1))) void*)g,
        (__attribute__((address_space(3))) void*)l,
        16, 0, 0);
}

// ---------------- preprocessing: f32 -> bf16 (+ transpose / swizzle) ----------------

__global__ __launch_bounds__(256)
void conv_inp(const float* __restrict__ in, unsigned short* __restrict__ out) {
    int i = (blockIdx.x * 256 + threadIdx.x) * 8;
    float4 a = *(const float4*)&in[i];
    float4 b = *(const float4*)&in[i + 4];
    union { unsigned short u[8]; s16x8 v; } r;
    r.u[0] = f2bf(a.x); r.u[1] = f2bf(a.y); r.u[2] = f2bf(a.z); r.u[3] = f2bf(a.w);
    r.u[4] = f2bf(b.x); r.u[5] = f2bf(b.y); r.u[6] = f2bf(b.z); r.u[7] = f2bf(b.w);
    *(s16x8*)&out[i] = r.v;
}

// WxT[j][col][k] = bf16(Wx[j][k][col]) stored swizzled: within each 32-k slice
// (4 chunks of 16B), true chunk ct is stored at position ct ^ ((col>>1)&3).
// Staged linearly via global_load_lds; the reader applies the same XOR.
__global__ __launch_bounds__(256)
void conv_wxT(const float* __restrict__ Wx, unsigned short* __restrict__ WxT) {
    __shared__ unsigned short T[64][80];
    int j  = blockIdx.y;
    int tr = blockIdx.x >> 3;   // k-tile
    int tc = blockIdx.x & 7;    // col-tile
    const float* src = Wx + (size_t)j * IN_DIM * IN_DIM;
    unsigned short* dst = WxT + (size_t)j * IN_DIM * IN_DIM;
    int tid = threadIdx.x;
    int k  = tid >> 2;
    int c0 = (tid & 3) * 16;
    for (int u = 0; u < 16; u += 4) {
        float4 v = *(const float4*)&src[(size_t)(tr * 64 + k) * IN_DIM + tc * 64 + c0 + u];
        T[c0 + u + 0][k] = f2bf(v.x);
        T[c0 + u + 1][k] = f2bf(v.y);
        T[c0 + u + 2][k] = f2bf(v.z);
        T[c0 + u + 3][k] = f2bf(v.w);
    }
    __syncthreads();
    int c   = tid >> 2;          // col within 64-col tile
    int k0b = (tid & 3) * 16;
    for (int u = 0; u < 16; u += 8) {
        int kk = k0b + u;                          // 0..56, multiple of 8
        int ct = (kk >> 3) & 3;                    // chunk within 32-k slice
        int pos = (kk & 32) | (((ct ^ ((c >> 1) & 3)) & 3) << 3);
        s16x8 v = *(const s16x8*)&T[c][kk];
        *(s16x8*)&dst[(size_t)(tc * 64 + c) * IN_DIM + tr * 64 + pos] = v;
    }
}

// WpT[j][w][k] = bf16(Wp[j][k][w])
__global__ __launch_bounds__(256)
void conv_wpT(const float* __restrict__ Wp, unsigned short* __restrict__ WpT) {
    int j = blockIdx.x;
    const float* src = Wp + (size_t)j * IN_DIM * 8;
    unsigned short* dst = WpT + (size_t)j * IN_DIM * 8;
    for (int k = threadIdx.x; k < IN_DIM; k += 256)
        for (int w = 0; w < 8; ++w)
            dst[w * IN_DIM + k] = f2bf(src[k * 8 + w]);
}

// ---------------- pipelined fused level kernel ----------------
__global__ __launch_bounds__(256, 2)
void level_pipe(const unsigned short* __restrict__ inpB,   // [8192][512] bf16
                const unsigned short* __restrict__ WxT,    // [n][col][k] bf16, chunk-swizzled
                const float* __restrict__ bx,
                const unsigned short* __restrict__ WpT,    // [n][8][512] bf16
                const float* __restrict__ bp,
                const float* __restrict__ parent,
                int pstride, int poff, int invert_parent,
                float* __restrict__ outp, int ostride)
{
    // lds union: 3 B-slots of 16 KB at [0,48K) ; Hsh [128][260] u16 at [0,66560B)
    extern __shared__ __align__(16) unsigned short lds[];

    const int tid  = threadIdx.x;
    const int lane = tid & 63;
    const int wv   = tid >> 6;        // 0..3 : col-quarter of the nt-half
    const int j    = blockIdx.y;
    const int rowBase = blockIdx.x * PH_BM;
    const int lr   = lane & 15;
    const int grp  = lane >> 4;       // 0..3
    const int kg8  = grp * 8;
    const int rg   = grp * 4;

    const unsigned short* WxTj = WxT + (size_t)j * IN_DIM * IN_DIM;
    const unsigned short* WpTj = WpT + (size_t)j * IN_DIM * 8;

    // staging: thread covers col = i*64 + wv*16 + (lane>>2), chunk (lane&3); LDS linear
    const unsigned short* gst0 = WxTj + (size_t)(wv * 16 + (lane >> 2)) * IN_DIM + (lane & 3) * 8;
    unsigned short* sdst0 = lds + wv * 512;   // wave-uniform; +i*2048, +slot; lane*16B implicit

    // A per-lane base: rows rowBase + mt*16 + lr, k = kg8 (+t*32)
    const unsigned short* aBase = inpB + (size_t)(rowBase + lr) * IN_DIM + kg8;

    // swizzled B-read offsets (u16) within a slot, per nn fragment
    int bro[4];
    #pragma unroll
    for (int nn = 0; nn < 4; ++nn) {
        int col = wv * 64 + nn * 16 + lr;
        bro[nn] = col * PH_BK + ((grp ^ ((col >> 1) & 3)) << 3);
    }

    f32x4 acc[8][4];
    f32x4 acc2[2] = {};
    s16x8 afA[8], afB[8];
    const unsigned short* gst = gst0;

    auto LOADA = [&](s16x8 (&af)[8], int t) {
        const unsigned short* ap = aBase + t * PH_BK;
        #pragma unroll
        for (int mt = 0; mt < 8; ++mt)
            af[mt] = *(const s16x8*)(ap + (size_t)(mt * 16) * IN_DIM);
    };
    auto STAGE = [&](int t) {
        unsigned short* sb = sdst0 + (t % 3) * SLOT_U16;
        const unsigned short* g = gst + t * PH_BK;
        #pragma unroll
        for (int i = 0; i < 4; ++i)
            gload16(g + (size_t)i * 64 * IN_DIM, sb + i * 2048);
    };
    auto MFMAS = [&](s16x8 (&afc)[8], int t) {
        const unsigned short* sr = lds + (t % 3) * SLOT_U16;
        s16x8 bf[4];
        #pragma unroll
        for (int nn = 0; nn < 4; ++nn)
            bf[nn] = *(const s16x8*)&sr[bro[nn]];
        asm volatile("s_waitcnt lgkmcnt(0)" ::: "memory");
        __builtin_amdgcn_sched_barrier(0);
        __builtin_amdgcn_s_setprio(1);
        #pragma unroll
        for (int mt = 0; mt < 8; ++mt)
            #pragma unroll
            for (int nn = 0; nn < 4; ++nn)
                acc[mt][nn] = __builtin_amdgcn_mfma_f32_16x16x32_bf16(
                    afc[mt], bf[nn], acc[mt][nn], 0, 0, 0);
        __builtin_amdgcn_s_setprio(0);
    };

    #pragma unroll 1
    for (int nt = 0; nt < 2; ++nt) {
        gst = gst0 + (size_t)nt * PH_BNT * IN_DIM;
        #pragma unroll
        for (int mt = 0; mt < 8; ++mt)
            #pragma unroll
            for (int nn = 0; nn < 4; ++nn)
                acc[mt][nn] = f32x4{0.f, 0.f, 0.f, 0.f};

        // prologue (issue order matters for vmcnt FIFO accounting): B(0), A(0), B(1)
        STAGE(0);
        LOADA(afA, 0);
        STAGE(1);

        // steady state: entry in-flight = {B(t):4, A(t):8, B(t+1):4} = 16
        // vmcnt(12) completes exactly B(t); A(t)/B(t+1) stay in flight.
        #pragma unroll 1
        for (int t = 0; t < 14; t += 2) {
            asm volatile("s_waitcnt vmcnt(12)" ::: "memory");
            __builtin_amdgcn_s_barrier();
            LOADA(afB, t + 1);
            STAGE(t + 2);
            MFMAS(afA, t);

            asm volatile("s_waitcnt vmcnt(12)" ::: "memory");
            __builtin_amdgcn_s_barrier();
            LOADA(afA, t + 2);
            STAGE(t + 3);
            MFMAS(afB, t + 1);
        }
        // phase 14: in-flight {B14:4, A14:8, B15:4} = 16
        asm volatile("s_waitcnt vmcnt(12)" ::: "memory");
        __builtin_amdgcn_s_barrier();
        LOADA(afB, 15);
        MFMAS(afA, 14);
        // phase 15: in-flight {B15:4, A15:8} = 12
        asm volatile("s_waitcnt vmcnt(8)" ::: "memory");
        __builtin_amdgcn_s_barrier();
        MFMAS(afB, 15);

        // ---- Hsh (overlays slots) + stage-2 ----
        __builtin_amdgcn_s_barrier();   // all waves done reading slots
        #pragma unroll
        for (int nn = 0; nn < 4; ++nn) {
            int ncol = wv * 64 + nn * 16 + lr;
            float bxv = bx[(size_t)j * IN_DIM + nt * PH_BNT + ncol];
            #pragma unroll
            for (int mt = 0; mt < 8; ++mt)
                #pragma unroll
                for (int v = 0; v < 4; ++v) {
                    float h = acc[mt][nn][v] + bxv;
                    h = h > 0.f ? h : 0.f;
                    lds[(mt * 16 + rg + v) * PH_HSTR + ncol] = f2bf(h);
                }
        }
        asm volatile("s_waitcnt lgkmcnt(0)" ::: "memory");
        __builtin_amdgcn_s_barrier();
        // stage-2: logits += Hsh @ WpT ; wave wv owns rows wv*32..+32
        #pragma unroll
        for (int k2 = 0; k2 < 8; ++k2) {
            s16x8 b2 = *(const s16x8*)(WpTj + (size_t)(lr & 7) * IN_DIM + nt * PH_BNT + k2 * 32 + kg8);
            #pragma unroll
            for (int m2 = 0; m2 < 2; ++m2) {
                s16x8 a2 = *(const s16x8*)&lds[(wv * 32 + m2 * 16 + lr) * PH_HSTR + k2 * 32 + kg8];
                acc2[m2] = __builtin_amdgcn_mfma_f32_16x16x32_bf16(a2, b2, acc2[m2], 0, 0, 0);
            }
        }
        __builtin_amdgcn_s_barrier();   // Hsh reads done before next nt's staging
    }

    // ---- softmax over 8 cols + parent scale + store ----
    bool valid = lr < 8;
    float bpv = valid ? bp[(size_t)j * 8 + lr] : 0.f;
    #pragma unroll
    for (int m2 = 0; m2 < 2; ++m2) {
        #pragma unroll
        for (int v = 0; v < 4; ++v) {
            float x = acc2[m2][v] + bpv;
            float mx = x;
            for (int d = 1; d < 8; d <<= 1)
                mx = fmaxf(mx, __shfl_xor(mx, d, 64));
            float e = __expf(x - mx);
            float s = e;
            for (int d = 1; d < 8; d <<= 1)
                s += __shfl_xor(s, d, 64);
            float p = e / s;
            int gb = rowBase + wv * 32 + m2 * 16 + rg + v;
            float pv = invert_parent ? (1.f - parent[(size_t)gb * pstride + poff])
                                     : parent[(size_t)gb * pstride + j];
            if (valid)
                outp[(size_t)gb * ostride + j * 8 + lr] = p * pv;
        }
    }
}

// ---------------- fallback (f32-direct) level kernel, used if ws too small ----------------
__global__ __launch_bounds__(256, 2)
void level_ref(const float* __restrict__ inp,
               const float* __restrict__ Wx,
               const float* __restrict__ bx,
               const float* __restrict__ Wp,
               const float* __restrict__ bp,
               const float* __restrict__ parent,
               int pstride, int poff, int invert_parent,
               float* __restrict__ outp, int ostride)
{
    __shared__ __align__(16) unsigned short Ash[128][40];
    __shared__ __align__(16) unsigned short Bsh[128][40];
    __shared__ __align__(16) unsigned short Hsh[128][136];
    __shared__ __align__(16) unsigned short WpSh[8][IN_DIM];

    const int tid  = threadIdx.x;
    const int lane = tid & 63;
    const int wv   = tid >> 6;
    const int j    = blockIdx.y;
    const int rowBase = blockIdx.x * 128;
    const int lr = lane & 15;
    const int kg = (lane >> 4) * 8;
    const int rg = (lane >> 4) * 4;
    const int wm = (wv & 1) * 64;
    const int wn = (wv >> 1) * 64;

    const float* WxJ = Wx + (size_t)j * IN_DIM * IN_DIM;
    const float* WpJ = Wp + (size_t)j * IN_DIM * 8;

    for (int i = tid; i < IN_DIM * 2; i += 256) {
        int k  = i >> 1;
        int w4 = (i & 1) * 4;
        float4 v = *(const float4*)&WpJ[k * 8 + w4];
        WpSh[w4 + 0][k] = f2bf(v.x);
        WpSh[w4 + 1][k] = f2bf(v.y);
        WpSh[w4 + 2][k] = f2bf(v.z);
        WpSh[w4 + 3][k] = f2bf(v.w);
    }

    f32x4 acc2[2] = {};

    for (int nt = 0; nt < 4; ++nt) {
        f32x4 acc[4][4] = {};
        for (int k0 = 0; k0 < IN_DIM; k0 += 32) {
            __syncthreads();
            {
                int kk4 = (tid & 7) * 4;
                int rb  = tid >> 3;
                for (int it = 0; it < 4; ++it) {
                    int r = rb + it * 32;
                    float4 v = *(const float4*)&inp[(size_t)(rowBase + r) * IN_DIM + k0 + kk4];
                    unsigned short* dst = &Ash[r][kk4];
                    dst[0] = f2bf(v.x); dst[1] = f2bf(v.y);
                    dst[2] = f2bf(v.z); dst[3] = f2bf(v.w);
                }
            }
            {
                int n4 = (tid & 31) * 4;
                int kb = tid >> 5;
                for (int it = 0; it < 4; ++it) {
                    int kk = kb + it * 8;
                    float4 v = *(const float4*)&WxJ[(size_t)(k0 + kk) * IN_DIM + nt * 128 + n4];
                    Bsh[n4 + 0][kk] = f2bf(v.x);
                    Bsh[n4 + 1][kk] = f2bf(v.y);
                    Bsh[n4 + 2][kk] = f2bf(v.z);
                    Bsh[n4 + 3][kk] = f2bf(v.w);
                }
            }
            __syncthreads();
            s16x8 af[4], bfr[4];
            for (int mt = 0; mt < 4; ++mt)
                af[mt] = *(const s16x8*)&Ash[wm + mt * 16 + lr][kg];
            for (int nn = 0; nn < 4; ++nn)
                bfr[nn] = *(const s16x8*)&Bsh[wn + nn * 16 + lr][kg];
            for (int mt = 0; mt < 4; ++mt)
                for (int nn = 0; nn < 4; ++nn)
                    acc[mt][nn] = __builtin_amdgcn_mfma_f32_16x16x32_bf16(
                        af[mt], bfr[nn], acc[mt][nn], 0, 0, 0);
        }
        __syncthreads();
        for (int nn = 0; nn < 4; ++nn) {
            int ncol = wn + nn * 16 + lr;
            float bxv = bx[(size_t)j * IN_DIM + nt * 128 + ncol];
            for (int mt = 0; mt < 4; ++mt)
                for (int v = 0; v < 4; ++v) {
                    float h = acc[mt][nn][v] + bxv;
                    h = h > 0.f ? h : 0.f;
                    Hsh[wm + mt * 16 + rg + v][ncol] = f2bf(h);
                }
        }
        __syncthreads();
        {
            s16x8 zero = {};
            for (int k2 = 0; k2 < 128; k2 += 32) {
                s16x8 b2 = (lr < 8) ? *(const s16x8*)&WpSh[lr][nt * 128 + k2 + kg] : zero;
                for (int m2 = 0; m2 < 2; ++m2) {
                    s16x8 a2 = *(const s16x8*)&Hsh[wv * 32 + m2 * 16 + lr][k2 + kg];
                    acc2[m2] = __builtin_amdgcn_mfma_f32_16x16x32_bf16(a2, b2, acc2[m2], 0, 0, 0);
                }
            }
        }
    }

    bool valid = lr < 8;
    float bpv = valid ? bp[(size_t)j * 8 + lr] : 0.f;
    for (int m2 = 0; m2 < 2; ++m2) {
        for (int v = 0; v < 4; ++v) {
            float x = acc2[m2][v] + bpv;
            float mx = x;
            for (int d = 1; d < 8; d <<= 1)
                mx = fmaxf(mx, __shfl_xor(mx, d, 64));
            float e = __expf(x - mx);
            float s = e;
            for (int d = 1; d < 8; d <<= 1)
                s += __shfl_xor(s, d, 64);
            float p = e / s;
            int gb = rowBase + wv * 32 + m2 * 16 + rg + v;
            float pv = invert_parent ? (1.f - parent[(size_t)gb * pstride + poff])
                                     : parent[(size_t)gb * pstride + j];
            if (valid)
                outp[(size_t)gb * ostride + j * 8 + lr] = p * pv;
        }
    }
}

// got_event head
__global__ __launch_bounds__(256)
void head_kernel(const float* __restrict__ inp,
                 const float* __restrict__ We,
                 const float* __restrict__ be,
                 float* __restrict__ out)
{
    int row  = blockIdx.x * 4 + (threadIdx.x >> 6);
    int lane = threadIdx.x & 63;
    const float* ip = inp + (size_t)row * IN_DIM;
    float4 a0 = *(const float4*)&ip[lane * 8];
    float4 a1 = *(const float4*)&ip[lane * 8 + 4];
    float4 w0 = *(const float4*)&We[lane * 8];
    float4 w1 = *(const float4*)&We[lane * 8 + 4];
    float s = a0.x*w0.x + a0.y*w0.y + a0.z*w0.z + a0.w*w0.w
            + a1.x*w1.x + a1.y*w1.y + a1.z*w1.z + a1.w*w1.w;
    for (int d = 1; d < 64; d <<= 1)
        s += __shfl_xor(s, d, 64);
    if (lane == 0) {
        float ge = 1.f / (1.f + __expf(-(s + be[0])));
        float og = 1.f - ge;
        out[(size_t)row * 9 + 8] = og;
        out[(size_t)(NBATCH * 9) + (size_t)row * 65 + 64] = og;
        out[(size_t)(NBATCH * 9 + NBATCH * 65) + (size_t)row * 513 + 512] = og;
    }
}

extern "C" void kernel_launch(void* const* d_in, const int* in_sizes, int n_in,
                              void* d_out, int out_size, void* d_ws, size_t ws_size,
                              hipStream_t stream) {
    const float* inp = (const float*)d_in[0];
    const float* Wx0 = (const float*)d_in[1];
    const float* bx0 = (const float*)d_in[2];
    const float* Wp0 = (const float*)d_in[3];
    const float* bp0 = (const float*)d_in[4];
    const float* Wx1 = (const float*)d_in[5];
    const float* bx1 = (const float*)d_in[6];
    const float* Wp1 = (const float*)d_in[7];
    const float* bp1 = (const float*)d_in[8];
    const float* Wx2 = (const float*)d_in[9];
    const float* bx2 = (const float*)d_in[10];
    const float* Wp2 = (const float*)d_in[11];
    const float* bp2 = (const float*)d_in[12];
    const float* We  = (const float*)d_in[13];
    const float* be  = (const float*)d_in[14];
    float* out = (float*)d_out;

    const size_t OUT1 = (size_t)NBATCH * 9;
    const size_t OUT2 = OUT1 + (size_t)NBATCH * 65;

    const size_t INP_E = (size_t)NBATCH * IN_DIM;
    const size_t WX_E  = (size_t)IN_DIM * IN_DIM;
    const size_t WP_E  = (size_t)IN_DIM * 8;
    const size_t NEED  = 2 * (INP_E + 73 * WX_E + 73 * WP_E);

    head_kernel<<<NBATCH / 4, 256, 0, stream>>>(inp, We, be, out);

    dim3 blk(256);
    bool fast = false;
    if (ws_size >= NEED) {
        hipError_t rc = hipFuncSetAttribute((const void*)level_pipe,
                                            hipFuncAttributeMaxDynamicSharedMemorySize,
                                            PH_LDS_BYTES);
        fast = (rc == hipSuccess);
    }

    if (fast) {
        unsigned short* inpB   = (unsigned short*)d_ws;
        unsigned short* WxTall = inpB + INP_E;
        unsigned short* WpTall = WxTall + 73 * WX_E;

        conv_inp<<<NBATCH * IN_DIM / (256 * 8), 256, 0, stream>>>(inp, inpB);
        conv_wxT<<<dim3(64, 1),  blk, 0, stream>>>(Wx0, WxTall);
        conv_wxT<<<dim3(64, 8),  blk, 0, stream>>>(Wx1, WxTall + 1 * WX_E);
        conv_wxT<<<dim3(64, 64), blk, 0, stream>>>(Wx2, WxTall + 9 * WX_E);
        conv_wpT<<<1,  blk, 0, stream>>>(Wp0, WpTall);
        conv_wpT<<<8,  blk, 0, stream>>>(Wp1, WpTall + 1 * WP_E);
        conv_wpT<<<64, blk, 0, stream>>>(Wp2, WpTall + 9 * WP_E);

        level_pipe<<<dim3(NBATCH / PH_BM, 1), blk, PH_LDS_BYTES, stream>>>(
            inpB, WxTall, bx0, WpTall, bp0, out, 9, 8, 1, out, 9);
        level_pipe<<<dim3(NBATCH / PH_BM, 8), blk, PH_LDS_BYTES, stream>>>(
            inpB, WxTall + 1 * WX_E, bx1, WpTall + 1 * WP_E, bp1,
            out, 9, 0, 0, out + OUT1, 65);
        level_pipe<<<dim3(NBATCH / PH_BM, 64), blk, PH_LDS_BYTES, stream>>>(
            inpB, WxTall + 9 * WX_E, bx2, WpTall + 9 * WP_E, bp2,
            out + OUT1, 65, 0, 0, out + OUT2, 513);
    } else {
        level_ref<<<dim3(NBATCH / 128, 1), blk, 0, stream>>>(
            inp, Wx0, bx0, Wp0, bp0, out, 9, 8, 1, out, 9);
        level_ref<<<dim3(NBATCH / 128, 8), blk, 0, stream>>>(
            inp, Wx1, bx1, Wp1, bp1, out, 9, 0, 0, out + OUT1, 65);
        level_ref<<<dim3(NBATCH / 128, 64), blk, 0, stream>>>(
            inp, Wx2, bx2, Wp2, bp2, out + OUT1, 65, 0, 0, out + OUT2, 513);
    }
}

// Round 7
// 589.623 us; speedup vs baseline: 1.5292x; 1.5292x over previous
//
#include <hip/hip_runtime.h>

#define IN_DIM 512
#define NBATCH 8192

// ---- pipelined kernel geometry: 128 rows x 256-col half, 4 waves of 64x128, BK=32 ----
#define PH_BM 128
#define PH_BNT 256
#define PH_BK 32
#define SLOT_U16 8192                     // 16 KB B-slot ([256 col][32 k] bf16), 3 slots
#define PH_HSTR 264                       // Hsh stride u16 (528 B, 16B-aligned rows)
#define PH_LDS_BYTES (PH_BM * PH_HSTR * 2)   // 67,584 B (3 slots = 48 KB overlaid at offset 0)

typedef short s16x8 __attribute__((ext_vector_type(8)));
typedef float f32x4 __attribute__((ext_vector_type(4)));

__device__ __forceinline__ unsigned short f2bf(float f) {
    union { float f; unsigned int u; } c;
    c.f = f;
    unsigned int u = c.u;
    u += 0x7fffu + ((u >> 16) & 1u);   // round-to-nearest-even
    return (unsigned short)(u >> 16);
}

__device__ __forceinline__ void gload16(const unsigned short* g, unsigned short* l) {
    __builtin_amdgcn_global_load_lds(
        (const __attribute__((address_space(1))) void*)g,
        (__attribute__((address_space(3))) void*)l,
        16, 0, 0);
}

// ---------------- preprocessing: f32 -> bf16 (+ transpose / swizzle) ----------------

__global__ __launch_bounds__(256)
void conv_inp(const float* __restrict__ in, unsigned short* __restrict__ out) {
    int i = (blockIdx.x * 256 + threadIdx.x) * 8;
    float4 a = *(const float4*)&in[i];
    float4 b = *(const float4*)&in[i + 4];
    union { unsigned short u[8]; s16x8 v; } r;
    r.u[0] = f2bf(a.x); r.u[1] = f2bf(a.y); r.u[2] = f2bf(a.z); r.u[3] = f2bf(a.w);
    r.u[4] = f2bf(b.x); r.u[5] = f2bf(b.y); r.u[6] = f2bf(b.z); r.u[7] = f2bf(b.w);
    *(s16x8*)&out[i] = r.v;
}

// WxT[j][col][k] = bf16(Wx[j][k][col]) stored swizzled: within each 32-k slice
// (4 chunks of 16B), true chunk ct is stored at position ct ^ ((col>>1)&3).
// Staged linearly via global_load_lds; the reader applies the same XOR.
__global__ __launch_bounds__(256)
void conv_wxT(const float* __restrict__ Wx, unsigned short* __restrict__ WxT) {
    __shared__ unsigned short T[64][80];
    int j  = blockIdx.y;
    int tr = blockIdx.x >> 3;   // k-tile
    int tc = blockIdx.x & 7;    // col-tile
    const float* src = Wx + (size_t)j * IN_DIM * IN_DIM;
    unsigned short* dst = WxT + (size_t)j * IN_DIM * IN_DIM;
    int tid = threadIdx.x;
    int k  = tid >> 2;
    int c0 = (tid & 3) * 16;
    for (int u = 0; u < 16; u += 4) {
        float4 v = *(const float4*)&src[(size_t)(tr * 64 + k) * IN_DIM + tc * 64 + c0 + u];
        T[c0 + u + 0][k] = f2bf(v.x);
        T[c0 + u + 1][k] = f2bf(v.y);
        T[c0 + u + 2][k] = f2bf(v.z);
        T[c0 + u + 3][k] = f2bf(v.w);
    }
    __syncthreads();
    int c   = tid >> 2;          // col within 64-col tile
    int k0b = (tid & 3) * 16;
    for (int u = 0; u < 16; u += 8) {
        int kk = k0b + u;                          // 0..56, multiple of 8
        int ct = (kk >> 3) & 3;                    // chunk within 32-k slice
        int pos = (kk & 32) | (((ct ^ ((c >> 1) & 3)) & 3) << 3);
        s16x8 v = *(const s16x8*)&T[c][kk];
        *(s16x8*)&dst[(size_t)(tc * 64 + c) * IN_DIM + tr * 64 + pos] = v;
    }
}

// WpT[j][w][k] = bf16(Wp[j][k][w])
__global__ __launch_bounds__(256)
void conv_wpT(const float* __restrict__ Wp, unsigned short* __restrict__ WpT) {
    int j = blockIdx.x;
    const float* src = Wp + (size_t)j * IN_DIM * 8;
    unsigned short* dst = WpT + (size_t)j * IN_DIM * 8;
    for (int k = threadIdx.x; k < IN_DIM; k += 256)
        for (int w = 0; w < 8; ++w)
            dst[w * IN_DIM + k] = f2bf(src[k * 8 + w]);
}

// ---------------- macros (no lambdas / array-by-ref: keeps everything in VGPRs) ----------------

#define PH_LOADA(d0, d1, d2, d3, t) do {                         \
    const unsigned short* ap_ = aBase + (t) * PH_BK;             \
    d0 = *(const s16x8*)(ap_);                                   \
    d1 = *(const s16x8*)(ap_ + 16 * (size_t)IN_DIM);             \
    d2 = *(const s16x8*)(ap_ + 32 * (size_t)IN_DIM);             \
    d3 = *(const s16x8*)(ap_ + 48 * (size_t)IN_DIM);             \
} while (0)

#define PH_STAGE(t) do {                                         \
    unsigned short* sb_ = sdst0 + ((t) % 3) * SLOT_U16;          \
    const unsigned short* g_ = gst + (size_t)(t) * PH_BK;        \
    gload16(g_,                         sb_);                    \
    gload16(g_ +  64 * (size_t)IN_DIM,  sb_ + 2048);             \
    gload16(g_ + 128 * (size_t)IN_DIM,  sb_ + 4096);             \
    gload16(g_ + 192 * (size_t)IN_DIM,  sb_ + 6144);             \
} while (0)

#define PH_MFMA(a0, a1, a2_, a3, t) do {                         \
    const unsigned short* sr_ = lds + ((t) % 3) * SLOT_U16;      \
    s16x8 bf_[8];                                                \
    _Pragma("unroll")                                            \
    for (int nn = 0; nn < 8; ++nn)                               \
        bf_[nn] = *(const s16x8*)&sr_[bro[nn]];                  \
    asm volatile("s_waitcnt lgkmcnt(0)" ::: "memory");           \
    __builtin_amdgcn_sched_barrier(0);                           \
    __builtin_amdgcn_s_setprio(1);                               \
    _Pragma("unroll")                                            \
    for (int nn = 0; nn < 8; ++nn) {                             \
        acc[0][nn] = __builtin_amdgcn_mfma_f32_16x16x32_bf16(a0,  bf_[nn], acc[0][nn], 0, 0, 0); \
        acc[1][nn] = __builtin_amdgcn_mfma_f32_16x16x32_bf16(a1,  bf_[nn], acc[1][nn], 0, 0, 0); \
        acc[2][nn] = __builtin_amdgcn_mfma_f32_16x16x32_bf16(a2_, bf_[nn], acc[2][nn], 0, 0, 0); \
        acc[3][nn] = __builtin_amdgcn_mfma_f32_16x16x32_bf16(a3,  bf_[nn], acc[3][nn], 0, 0, 0); \
    }                                                            \
    __builtin_amdgcn_s_setprio(0);                               \
} while (0)

// ---------------- pipelined fused level kernel ----------------
__global__ __launch_bounds__(256, 2)
void level_pipe(const unsigned short* __restrict__ inpB,   // [8192][512] bf16
                const unsigned short* __restrict__ WxT,    // [n][col][k] bf16, chunk-swizzled
                const float* __restrict__ bx,
                const unsigned short* __restrict__ WpT,    // [n][8][512] bf16
                const float* __restrict__ bp,
                const float* __restrict__ parent,
                int pstride, int poff, int invert_parent,
                float* __restrict__ outp, int ostride)
{
    // lds union: 3 B-slots of 16 KB at [0,48K) ; Hsh [128][264] u16 at [0,67584B)
    extern __shared__ __align__(16) unsigned short lds[];

    const int tid  = threadIdx.x;
    const int lane = tid & 63;
    const int wv   = tid >> 6;        // 0..3
    const int wr   = wv & 1;          // row half (64 rows)
    const int wc   = wv >> 1;         // col half (128 cols of the 256-col chunk)
    const int j    = blockIdx.y;
    const int rowBase = blockIdx.x * PH_BM;
    const int lr   = lane & 15;
    const int grp  = lane >> 4;       // 0..3
    const int kg8  = grp * 8;
    const int rg   = grp * 4;

    const unsigned short* WxTj = WxT + (size_t)j * IN_DIM * IN_DIM;
    const unsigned short* WpTj = WpT + (size_t)j * IN_DIM * 8;

    // staging: thread covers col = i*64 + wv*16 + (lane>>2), chunk (lane&3); LDS linear
    const unsigned short* gst0 = WxTj + (size_t)(wv * 16 + (lane >> 2)) * IN_DIM + (lane & 3) * 8;
    unsigned short* sdst0 = lds + wv * 512;   // wave-uniform; lane*16B implicit

    // A per-lane base: rows rowBase + wr*64 + mt*16 + lr, k = kg8 (+t*32)
    const unsigned short* aBase = inpB + (size_t)(rowBase + wr * 64 + lr) * IN_DIM + kg8;

    // swizzled B-read offsets (u16) within a slot, per nn fragment
    int bro[8];
    #pragma unroll
    for (int nn = 0; nn < 8; ++nn) {
        int col = wc * 128 + nn * 16 + lr;
        bro[nn] = col * PH_BK + (((grp ^ ((col >> 1) & 3)) & 3) << 3);
    }

    f32x4 acc[4][8];
    f32x4 acc2[2] = {};
    s16x8 afA0, afA1, afA2, afA3, afB0, afB1, afB2, afB3;
    const unsigned short* gst = gst0;

    #pragma unroll 1
    for (int nt = 0; nt < 2; ++nt) {
        gst = gst0 + (size_t)nt * PH_BNT * IN_DIM;
        #pragma unroll
        for (int mt = 0; mt < 4; ++mt)
            #pragma unroll
            for (int nn = 0; nn < 8; ++nn)
                acc[mt][nn] = f32x4{0.f, 0.f, 0.f, 0.f};

        // prologue FIFO: B(0):4, A(0):4, B(1):4  -> 12 outstanding
        PH_STAGE(0);
        PH_LOADA(afA0, afA1, afA2, afA3, 0);
        PH_STAGE(1);

        // steady state: entry outstanding = {B(t):4, A(t):4, B(t+1):4} = 12
        // vmcnt(8) completes exactly B(t); A(t)/B(t+1) stay in flight (compiler's
        // own counted wait before the MFMAs covers A(t)).
        #pragma unroll 1
        for (int t = 0; t < 14; t += 2) {
            asm volatile("s_waitcnt vmcnt(8)" ::: "memory");
            __builtin_amdgcn_s_barrier();
            PH_LOADA(afB0, afB1, afB2, afB3, t + 1);
            PH_STAGE(t + 2);
            PH_MFMA(afA0, afA1, afA2, afA3, t);

            asm volatile("s_waitcnt vmcnt(8)" ::: "memory");
            __builtin_amdgcn_s_barrier();
            PH_LOADA(afA0, afA1, afA2, afA3, t + 2);
            PH_STAGE(t + 3);
            PH_MFMA(afB0, afB1, afB2, afB3, t + 1);
        }
        // phase 14: outstanding {B14:4, A14:4, B15:4} = 12
        asm volatile("s_waitcnt vmcnt(8)" ::: "memory");
        __builtin_amdgcn_s_barrier();
        PH_LOADA(afB0, afB1, afB2, afB3, 15);
        PH_MFMA(afA0, afA1, afA2, afA3, 14);
        // phase 15: outstanding {B15:4, A15:4} = 8
        asm volatile("s_waitcnt vmcnt(4)" ::: "memory");
        __builtin_amdgcn_s_barrier();
        PH_MFMA(afB0, afB1, afB2, afB3, 15);

        // ---- Hsh (overlays slots) + stage-2 ----
        __builtin_amdgcn_s_barrier();   // all waves done reading slots
        #pragma unroll
        for (int nn = 0; nn < 8; ++nn) {
            int ncol = wc * 128 + nn * 16 + lr;
            float bxv = bx[(size_t)j * IN_DIM + nt * PH_BNT + ncol];
            #pragma unroll
            for (int mt = 0; mt < 4; ++mt)
                #pragma unroll
                for (int v = 0; v < 4; ++v) {
                    float h = acc[mt][nn][v] + bxv;
                    h = h > 0.f ? h : 0.f;
                    lds[(wr * 64 + mt * 16 + rg + v) * PH_HSTR + ncol] = f2bf(h);
                }
        }
        asm volatile("s_waitcnt lgkmcnt(0)" ::: "memory");
        __builtin_amdgcn_s_barrier();
        // stage-2: logits += Hsh @ WpT ; wave wv owns rows wv*32..+32
        #pragma unroll
        for (int k2 = 0; k2 < 8; ++k2) {
            s16x8 b2 = *(const s16x8*)(WpTj + (size_t)(lr & 7) * IN_DIM + nt * PH_BNT + k2 * 32 + kg8);
            #pragma unroll
            for (int m2 = 0; m2 < 2; ++m2) {
                s16x8 a2 = *(const s16x8*)&lds[(wv * 32 + m2 * 16 + lr) * PH_HSTR + k2 * 32 + kg8];
                acc2[m2] = __builtin_amdgcn_mfma_f32_16x16x32_bf16(a2, b2, acc2[m2], 0, 0, 0);
            }
        }
        __builtin_amdgcn_s_barrier();   // Hsh reads done before next nt's staging
    }

    // ---- softmax over 8 cols + parent scale + store ----
    bool valid = lr < 8;
    float bpv = valid ? bp[(size_t)j * 8 + lr] : 0.f;
    #pragma unroll
    for (int m2 = 0; m2 < 2; ++m2) {
        #pragma unroll
        for (int v = 0; v < 4; ++v) {
            float x = acc2[m2][v] + bpv;
            float mx = x;
            for (int d = 1; d < 8; d <<= 1)
                mx = fmaxf(mx, __shfl_xor(mx, d, 64));
            float e = __expf(x - mx);
            float s = e;
            for (int d = 1; d < 8; d <<= 1)
                s += __shfl_xor(s, d, 64);
            float p = e / s;
            int gb = rowBase + wv * 32 + m2 * 16 + rg + v;
            float pv = invert_parent ? (1.f - parent[(size_t)gb * pstride + poff])
                                     : parent[(size_t)gb * pstride + j];
            if (valid)
                outp[(size_t)gb * ostride + j * 8 + lr] = p * pv;
        }
    }
}

// ---------------- fallback (f32-direct) level kernel, used if ws too small ----------------
__global__ __launch_bounds__(256, 2)
void level_ref(const float* __restrict__ inp,
               const float* __restrict__ Wx,
               const float* __restrict__ bx,
               const float* __restrict__ Wp,
               const float* __restrict__ bp,
               const float* __restrict__ parent,
               int pstride, int poff, int invert_parent,
               float* __restrict__ outp, int ostride)
{
    __shared__ __align__(16) unsigned short Ash[128][40];
    __shared__ __align__(16) unsigned short Bsh[128][40];
    __shared__ __align__(16) unsigned short Hsh[128][136];
    __shared__ __align__(16) unsigned short WpSh[8][IN_DIM];

    const int tid  = threadIdx.x;
    const int lane = tid & 63;
    const int wv   = tid >> 6;
    const int j    = blockIdx.y;
    const int rowBase = blockIdx.x * 128;
    const int lr = lane & 15;
    const int kg = (lane >> 4) * 8;
    const int rg = (lane >> 4) * 4;
    const int wm = (wv & 1) * 64;
    const int wn = (wv >> 1) * 64;

    const float* WxJ = Wx + (size_t)j * IN_DIM * IN_DIM;
    const float* WpJ = Wp + (size_t)j * IN_DIM * 8;

    for (int i = tid; i < IN_DIM * 2; i += 256) {
        int k  = i >> 1;
        int w4 = (i & 1) * 4;
        float4 v = *(const float4*)&WpJ[k * 8 + w4];
        WpSh[w4 + 0][k] = f2bf(v.x);
        WpSh[w4 + 1][k] = f2bf(v.y);
        WpSh[w4 + 2][k] = f2bf(v.z);
        WpSh[w4 + 3][k] = f2bf(v.w);
    }

    f32x4 acc2[2] = {};

    for (int nt = 0; nt < 4; ++nt) {
        f32x4 acc[4][4] = {};
        for (int k0 = 0; k0 < IN_DIM; k0 += 32) {
            __syncthreads();
            {
                int kk4 = (tid & 7) * 4;
                int rb  = tid >> 3;
                for (int it = 0; it < 4; ++it) {
                    int r = rb + it * 32;
                    float4 v = *(const float4*)&inp[(size_t)(rowBase + r) * IN_DIM + k0 + kk4];
                    unsigned short* dst = &Ash[r][kk4];
                    dst[0] = f2bf(v.x); dst[1] = f2bf(v.y);
                    dst[2] = f2bf(v.z); dst[3] = f2bf(v.w);
                }
            }
            {
                int n4 = (tid & 31) * 4;
                int kb = tid >> 5;
                for (int it = 0; it < 4; ++it) {
                    int kk = kb + it * 8;
                    float4 v = *(const float4*)&WxJ[(size_t)(k0 + kk) * IN_DIM + nt * 128 + n4];
                    Bsh[n4 + 0][kk] = f2bf(v.x);
                    Bsh[n4 + 1][kk] = f2bf(v.y);
                    Bsh[n4 + 2][kk] = f2bf(v.z);
                    Bsh[n4 + 3][kk] = f2bf(v.w);
                }
            }
            __syncthreads();
            s16x8 af[4], bfr[4];
            for (int mt = 0; mt < 4; ++mt)
                af[mt] = *(const s16x8*)&Ash[wm + mt * 16 + lr][kg];
            for (int nn = 0; nn < 4; ++nn)
                bfr[nn] = *(const s16x8*)&Bsh[wn + nn * 16 + lr][kg];
            for (int mt = 0; mt < 4; ++mt)
                for (int nn = 0; nn < 4; ++nn)
                    acc[mt][nn] = __builtin_amdgcn_mfma_f32_16x16x32_bf16(
                        af[mt], bfr[nn], acc[mt][nn], 0, 0, 0);
        }
        __syncthreads();
        for (int nn = 0; nn < 4; ++nn) {
            int ncol = wn + nn * 16 + lr;
            float bxv = bx[(size_t)j * IN_DIM + nt * 128 + ncol];
            for (int mt = 0; mt < 4; ++mt)
                for (int v = 0; v < 4; ++v) {
                    float h = acc[mt][nn][v] + bxv;
                    h = h > 0.f ? h : 0.f;
                    Hsh[wm + mt * 16 + rg + v][ncol] = f2bf(h);
                }
        }
        __syncthreads();
        {
            s16x8 zero = {};
            for (int k2 = 0; k2 < 128; k2 += 32) {
                s16x8 b2 = (lr < 8) ? *(const s16x8*)&WpSh[lr][nt * 128 + k2 + kg] : zero;
                for (int m2 = 0; m2 < 2; ++m2) {
                    s16x8 a2 = *(const s16x8*)&Hsh[wv * 32 + m2 * 16 + lr][k2 + kg];
                    acc2[m2] = __builtin_amdgcn_mfma_f32_16x16x32_bf16(a2, b2, acc2[m2], 0, 0, 0);
                }
            }
        }
    }

    bool valid = lr < 8;
    float bpv = valid ? bp[(size_t)j * 8 + lr] : 0.f;
    for (int m2 = 0; m2 < 2; ++m2) {
        for (int v = 0; v < 4; ++v) {
            float x = acc2[m2][v] + bpv;
            float mx = x;
            for (int d = 1; d < 8; d <<= 1)
                mx = fmaxf(mx, __shfl_xor(mx, d, 64));
            float e = __expf(x - mx);
            float s = e;
            for (int d = 1; d < 8; d <<= 1)
                s += __shfl_xor(s, d, 64);
            float p = e / s;
            int gb = rowBase + wv * 32 + m2 * 16 + rg + v;
            float pv = invert_parent ? (1.f - parent[(size_t)gb * pstride + poff])
                                     : parent[(size_t)gb * pstride + j];
            if (valid)
                outp[(size_t)gb * ostride + j * 8 + lr] = p * pv;
        }
    }
}

// got_event head
__global__ __launch_bounds__(256)
void head_kernel(const float* __restrict__ inp,
                 const float* __restrict__ We,
                 const float* __restrict__ be,
                 float* __restrict__ out)
{
    int row  = blockIdx.x * 4 + (threadIdx.x >> 6);
    int lane = threadIdx.x & 63;
    const float* ip = inp + (size_t)row * IN_DIM;
    float4 a0 = *(const float4*)&ip[lane * 8];
    float4 a1 = *(const float4*)&ip[lane * 8 + 4];
    float4 w0 = *(const float4*)&We[lane * 8];
    float4 w1 = *(const float4*)&We[lane * 8 + 4];
    float s = a0.x*w0.x + a0.y*w0.y + a0.z*w0.z + a0.w*w0.w
            + a1.x*w1.x + a1.y*w1.y + a1.z*w1.z + a1.w*w1.w;
    for (int d = 1; d < 64; d <<= 1)
        s += __shfl_xor(s, d, 64);
    if (lane == 0) {
        float ge = 1.f / (1.f + __expf(-(s + be[0])));
        float og = 1.f - ge;
        out[(size_t)row * 9 + 8] = og;
        out[(size_t)(NBATCH * 9) + (size_t)row * 65 + 64] = og;
        out[(size_t)(NBATCH * 9 + NBATCH * 65) + (size_t)row * 513 + 512] = og;
    }
}

extern "C" void kernel_launch(void* const* d_in, const int* in_sizes, int n_in,
                              void* d_out, int out_size, void* d_ws, size_t ws_size,
                              hipStream_t stream) {
    const float* inp = (const float*)d_in[0];
    const float* Wx0 = (const float*)d_in[1];
    const float* bx0 = (const float*)d_in[2];
    const float* Wp0 = (const float*)d_in[3];
    const float* bp0 = (const float*)d_in[4];
    const float* Wx1 = (const float*)d_in[5];
    const float* bx1 = (const float*)d_in[6];
    const float* Wp1 = (const float*)d_in[7];
    const float* bp1 = (const float*)d_in[8];
    const float* Wx2 = (const float*)d_in[9];
    const float* bx2 = (const float*)d_in[10];
    const float* Wp2 = (const float*)d_in[11];
    const float* bp2 = (const float*)d_in[12];
    const float* We  = (const float*)d_in[13];
    const float* be  = (const float*)d_in[14];
    float* out = (float*)d_out;

    const size_t OUT1 = (size_t)NBATCH * 9;
    const size_t OUT2 = OUT1 + (size_t)NBATCH * 65;

    const size_t INP_E = (size_t)NBATCH * IN_DIM;
    const size_t WX_E  = (size_t)IN_DIM * IN_DIM;
    const size_t WP_E  = (size_t)IN_DIM * 8;
    const size_t NEED  = 2 * (INP_E + 73 * WX_E + 73 * WP_E);

    head_kernel<<<NBATCH / 4, 256, 0, stream>>>(inp, We, be, out);

    dim3 blk(256);
    bool fast = false;
    if (ws_size >= NEED) {
        hipError_t rc = hipFuncSetAttribute((const void*)level_pipe,
                                            hipFuncAttributeMaxDynamicSharedMemorySize,
                                            PH_LDS_BYTES);
        fast = (rc == hipSuccess);
    }

    if (fast) {
        unsigned short* inpB   = (unsigned short*)d_ws;
        unsigned short* WxTall = inpB + INP_E;
        unsigned short* WpTall = WxTall + 73 * WX_E;

        conv_inp<<<NBATCH * IN_DIM / (256 * 8), 256, 0, stream>>>(inp, inpB);
        conv_wxT<<<dim3(64, 1),  blk, 0, stream>>>(Wx0, WxTall);
        conv_wxT<<<dim3(64, 8),  blk, 0, stream>>>(Wx1, WxTall + 1 * WX_E);
        conv_wxT<<<dim3(64, 64), blk, 0, stream>>>(Wx2, WxTall + 9 * WX_E);
        conv_wpT<<<1,  blk, 0, stream>>>(Wp0, WpTall);
        conv_wpT<<<8,  blk, 0, stream>>>(Wp1, WpTall + 1 * WP_E);
        conv_wpT<<<64, blk, 0, stream>>>(Wp2, WpTall + 9 * WP_E);

        level_pipe<<<dim3(NBATCH / PH_BM, 1), blk, PH_LDS_BYTES, stream>>>(
            inpB, WxTall, bx0, WpTall, bp0, out, 9, 8, 1, out, 9);
        level_pipe<<<dim3(NBATCH / PH_BM, 8), blk, PH_LDS_BYTES, stream>>>(
            inpB, WxTall + 1 * WX_E, bx1, WpTall + 1 * WP_E, bp1,
            out, 9, 0, 0, out + OUT1, 65);
        level_pipe<<<dim3(NBATCH / PH_BM, 64), blk, PH_LDS_BYTES, stream>>>(
            inpB, WxTall + 9 * WX_E, bx2, WpTall + 9 * WP_E, bp2,
            out + OUT1, 65, 0, 0, out + OUT2, 513);
    } else {
        level_ref<<<dim3(NBATCH / 128, 1), blk, 0, stream>>>(
            inp, Wx0, bx0, Wp0, bp0, out, 9, 8, 1, out, 9);
        level_ref<<<dim3(NBATCH / 128, 8), blk, 0, stream>>>(
            inp, Wx1, bx1, Wp1, bp1, out, 9, 0, 0, out + OUT1, 65);
        level_ref<<<dim3(NBATCH / 128, 64), blk, 0, stream>>>(
            inp, Wx2, bx2, Wp2, bp2, out + OUT1, 65, 0, 0, out + OUT2, 513);
    }
}

// Round 8
// 556.589 us; speedup vs baseline: 1.6200x; 1.0594x over previous
//
#include <hip/hip_runtime.h>

#define IN_DIM 512
#define NBATCH 8192

// ---- pipelined kernel geometry: 128 rows x 256-col half, 4 waves of 64x128, BK=32 ----
#define PH_BM 128
#define PH_BNT 256
#define PH_BK 32
#define SLOT_U16 8192                     // 16 KB B-slot ([256 col][32 k] bf16), 3 slots
#define PH_HSTR 264                       // Hsh stride u16 (528 B, 16B-aligned rows)
#define PH_LDS_BYTES (PH_BM * PH_HSTR * 2)   // 67,584 B (3 slots = 48 KB overlaid at offset 0)

typedef short s16x8 __attribute__((ext_vector_type(8)));
typedef float f32x4 __attribute__((ext_vector_type(4)));

__device__ __forceinline__ unsigned short f2bf(float f) {
    union { float f; unsigned int u; } c;
    c.f = f;
    unsigned int u = c.u;
    u += 0x7fffu + ((u >> 16) & 1u);   // round-to-nearest-even
    return (unsigned short)(u >> 16);
}

__device__ __forceinline__ void gload16(const unsigned short* g, unsigned short* l) {
    __builtin_amdgcn_global_load_lds(
        (const __attribute__((address_space(1))) void*)g,
        (__attribute__((address_space(3))) void*)l,
        16, 0, 0);
}

// ---------------- preprocessing: f32 -> bf16 (+ transpose / swizzle) ----------------

__global__ __launch_bounds__(256)
void conv_inp(const float* __restrict__ in, unsigned short* __restrict__ out) {
    int i = (blockIdx.x * 256 + threadIdx.x) * 8;
    float4 a = *(const float4*)&in[i];
    float4 b = *(const float4*)&in[i + 4];
    union { unsigned short u[8]; s16x8 v; } r;
    r.u[0] = f2bf(a.x); r.u[1] = f2bf(a.y); r.u[2] = f2bf(a.z); r.u[3] = f2bf(a.w);
    r.u[4] = f2bf(b.x); r.u[5] = f2bf(b.y); r.u[6] = f2bf(b.z); r.u[7] = f2bf(b.w);
    *(s16x8*)&out[i] = r.v;
}

// WxT[j][col][k] = bf16(Wx[j][k][col]) stored swizzled: within each 32-k slice
// (4 chunks of 16B), true chunk ct is stored at position ct ^ ((col>>1)&3).
// Staged linearly via global_load_lds; the reader applies the same XOR.
__global__ __launch_bounds__(256)
void conv_wxT(const float* __restrict__ Wx, unsigned short* __restrict__ WxT) {
    __shared__ unsigned short T[64][80];
    int j  = blockIdx.y;
    int tr = blockIdx.x >> 3;   // k-tile
    int tc = blockIdx.x & 7;    // col-tile
    const float* src = Wx + (size_t)j * IN_DIM * IN_DIM;
    unsigned short* dst = WxT + (size_t)j * IN_DIM * IN_DIM;
    int tid = threadIdx.x;
    int k  = tid >> 2;
    int c0 = (tid & 3) * 16;
    for (int u = 0; u < 16; u += 4) {
        float4 v = *(const float4*)&src[(size_t)(tr * 64 + k) * IN_DIM + tc * 64 + c0 + u];
        T[c0 + u + 0][k] = f2bf(v.x);
        T[c0 + u + 1][k] = f2bf(v.y);
        T[c0 + u + 2][k] = f2bf(v.z);
        T[c0 + u + 3][k] = f2bf(v.w);
    }
    __syncthreads();
    int c   = tid >> 2;          // col within 64-col tile
    int k0b = (tid & 3) * 16;
    for (int u = 0; u < 16; u += 8) {
        int kk = k0b + u;                          // 0..56, multiple of 8
        int ct = (kk >> 3) & 3;                    // chunk within 32-k slice
        int pos = (kk & 32) | (((ct ^ ((c >> 1) & 3)) & 3) << 3);
        s16x8 v = *(const s16x8*)&T[c][kk];
        *(s16x8*)&dst[(size_t)(tc * 64 + c) * IN_DIM + tr * 64 + pos] = v;
    }
}

// WpT[j][w][k] = bf16(Wp[j][k][w])
__global__ __launch_bounds__(256)
void conv_wpT(const float* __restrict__ Wp, unsigned short* __restrict__ WpT) {
    int j = blockIdx.x;
    const float* src = Wp + (size_t)j * IN_DIM * 8;
    unsigned short* dst = WpT + (size_t)j * IN_DIM * 8;
    for (int k = threadIdx.x; k < IN_DIM; k += 256)
        for (int w = 0; w < 8; ++w)
            dst[w * IN_DIM + k] = f2bf(src[k * 8 + w]);
}

// ---------------- macros (no lambdas / array-by-ref: keeps everything in VGPRs) ----------------

#define PH_LOADA(t) do {                                         \
    const unsigned short* ap_ = aBase + (t) * PH_BK;             \
    afA0 = *(const s16x8*)(ap_);                                 \
    afA1 = *(const s16x8*)(ap_ + 16 * (size_t)IN_DIM);           \
    afA2 = *(const s16x8*)(ap_ + 32 * (size_t)IN_DIM);           \
    afA3 = *(const s16x8*)(ap_ + 48 * (size_t)IN_DIM);           \
} while (0)

#define PH_STAGE(t) do {                                         \
    unsigned short* sb_ = sdst0 + ((t) % 3) * SLOT_U16;          \
    const unsigned short* g_ = gst + (size_t)(t) * PH_BK;        \
    gload16(g_,                         sb_);                    \
    gload16(g_ +  64 * (size_t)IN_DIM,  sb_ + 2048);             \
    gload16(g_ + 128 * (size_t)IN_DIM,  sb_ + 4096);             \
    gload16(g_ + 192 * (size_t)IN_DIM,  sb_ + 6144);             \
} while (0)

// 32 MFMAs in two bf-halves of 4 fragments each (live bf = 16 VGPR)
#define PH_MFMA(t) do {                                          \
    const unsigned short* sr_ = lds + ((t) % 3) * SLOT_U16;      \
    s16x8 bf0_ = *(const s16x8*)&sr_[bro[0]];                    \
    s16x8 bf1_ = *(const s16x8*)&sr_[bro[1]];                    \
    s16x8 bf2_ = *(const s16x8*)&sr_[bro[2]];                    \
    s16x8 bf3_ = *(const s16x8*)&sr_[bro[3]];                    \
    asm volatile("s_waitcnt lgkmcnt(0)" ::: "memory");           \
    __builtin_amdgcn_sched_barrier(0);                           \
    __builtin_amdgcn_s_setprio(1);                               \
    acc[0][0] = __builtin_amdgcn_mfma_f32_16x16x32_bf16(afA0, bf0_, acc[0][0], 0, 0, 0); \
    acc[1][0] = __builtin_amdgcn_mfma_f32_16x16x32_bf16(afA1, bf0_, acc[1][0], 0, 0, 0); \
    acc[2][0] = __builtin_amdgcn_mfma_f32_16x16x32_bf16(afA2, bf0_, acc[2][0], 0, 0, 0); \
    acc[3][0] = __builtin_amdgcn_mfma_f32_16x16x32_bf16(afA3, bf0_, acc[3][0], 0, 0, 0); \
    acc[0][1] = __builtin_amdgcn_mfma_f32_16x16x32_bf16(afA0, bf1_, acc[0][1], 0, 0, 0); \
    acc[1][1] = __builtin_amdgcn_mfma_f32_16x16x32_bf16(afA1, bf1_, acc[1][1], 0, 0, 0); \
    acc[2][1] = __builtin_amdgcn_mfma_f32_16x16x32_bf16(afA2, bf1_, acc[2][1], 0, 0, 0); \
    acc[3][1] = __builtin_amdgcn_mfma_f32_16x16x32_bf16(afA3, bf1_, acc[3][1], 0, 0, 0); \
    acc[0][2] = __builtin_amdgcn_mfma_f32_16x16x32_bf16(afA0, bf2_, acc[0][2], 0, 0, 0); \
    acc[1][2] = __builtin_amdgcn_mfma_f32_16x16x32_bf16(afA1, bf2_, acc[1][2], 0, 0, 0); \
    acc[2][2] = __builtin_amdgcn_mfma_f32_16x16x32_bf16(afA2, bf2_, acc[2][2], 0, 0, 0); \
    acc[3][2] = __builtin_amdgcn_mfma_f32_16x16x32_bf16(afA3, bf2_, acc[3][2], 0, 0, 0); \
    acc[0][3] = __builtin_amdgcn_mfma_f32_16x16x32_bf16(afA0, bf3_, acc[0][3], 0, 0, 0); \
    acc[1][3] = __builtin_amdgcn_mfma_f32_16x16x32_bf16(afA1, bf3_, acc[1][3], 0, 0, 0); \
    acc[2][3] = __builtin_amdgcn_mfma_f32_16x16x32_bf16(afA2, bf3_, acc[2][3], 0, 0, 0); \
    acc[3][3] = __builtin_amdgcn_mfma_f32_16x16x32_bf16(afA3, bf3_, acc[3][3], 0, 0, 0); \
    __builtin_amdgcn_s_setprio(0);                               \
    bf0_ = *(const s16x8*)&sr_[bro[4]];                          \
    bf1_ = *(const s16x8*)&sr_[bro[5]];                          \
    bf2_ = *(const s16x8*)&sr_[bro[6]];                          \
    bf3_ = *(const s16x8*)&sr_[bro[7]];                          \
    asm volatile("s_waitcnt lgkmcnt(0)" ::: "memory");           \
    __builtin_amdgcn_sched_barrier(0);                           \
    __builtin_amdgcn_s_setprio(1);                               \
    acc[0][4] = __builtin_amdgcn_mfma_f32_16x16x32_bf16(afA0, bf0_, acc[0][4], 0, 0, 0); \
    acc[1][4] = __builtin_amdgcn_mfma_f32_16x16x32_bf16(afA1, bf0_, acc[1][4], 0, 0, 0); \
    acc[2][4] = __builtin_amdgcn_mfma_f32_16x16x32_bf16(afA2, bf0_, acc[2][4], 0, 0, 0); \
    acc[3][4] = __builtin_amdgcn_mfma_f32_16x16x32_bf16(afA3, bf0_, acc[3][4], 0, 0, 0); \
    acc[0][5] = __builtin_amdgcn_mfma_f32_16x16x32_bf16(afA0, bf1_, acc[0][5], 0, 0, 0); \
    acc[1][5] = __builtin_amdgcn_mfma_f32_16x16x32_bf16(afA1, bf1_, acc[1][5], 0, 0, 0); \
    acc[2][5] = __builtin_amdgcn_mfma_f32_16x16x32_bf16(afA2, bf1_, acc[2][5], 0, 0, 0); \
    acc[3][5] = __builtin_amdgcn_mfma_f32_16x16x32_bf16(afA3, bf1_, acc[3][5], 0, 0, 0); \
    acc[0][6] = __builtin_amdgcn_mfma_f32_16x16x32_bf16(afA0, bf2_, acc[0][6], 0, 0, 0); \
    acc[1][6] = __builtin_amdgcn_mfma_f32_16x16x32_bf16(afA1, bf2_, acc[1][6], 0, 0, 0); \
    acc[2][6] = __builtin_amdgcn_mfma_f32_16x16x32_bf16(afA2, bf2_, acc[2][6], 0, 0, 0); \
    acc[3][6] = __builtin_amdgcn_mfma_f32_16x16x32_bf16(afA3, bf2_, acc[3][6], 0, 0, 0); \
    acc[0][7] = __builtin_amdgcn_mfma_f32_16x16x32_bf16(afA0, bf3_, acc[0][7], 0, 0, 0); \
    acc[1][7] = __builtin_amdgcn_mfma_f32_16x16x32_bf16(afA1, bf3_, acc[1][7], 0, 0, 0); \
    acc[2][7] = __builtin_amdgcn_mfma_f32_16x16x32_bf16(afA2, bf3_, acc[2][7], 0, 0, 0); \
    acc[3][7] = __builtin_amdgcn_mfma_f32_16x16x32_bf16(afA3, bf3_, acc[3][7], 0, 0, 0); \
    __builtin_amdgcn_s_setprio(0);                               \
} while (0)

// ---------------- pipelined fused level kernel ----------------
__global__ __launch_bounds__(256, 2)
void level_pipe(const unsigned short* __restrict__ inpB,   // [8192][512] bf16
                const unsigned short* __restrict__ WxT,    // [n][col][k] bf16, chunk-swizzled
                const float* __restrict__ bx,
                const unsigned short* __restrict__ WpT,    // [n][8][512] bf16
                const float* __restrict__ bp,
                const float* __restrict__ parent,
                int pstride, int poff, int invert_parent,
                float* __restrict__ outp, int ostride)
{
    // lds union: 3 B-slots of 16 KB at [0,48K) ; Hsh [128][264] u16 at [0,67584B)
    extern __shared__ __align__(16) unsigned short lds[];

    const int tid  = threadIdx.x;
    const int lane = tid & 63;
    const int wv   = tid >> 6;        // 0..3
    const int wr   = wv & 1;          // row half (64 rows)
    const int wc   = wv >> 1;         // col half (128 cols of the 256-col chunk)
    const int j    = blockIdx.y;
    const int rowBase = blockIdx.x * PH_BM;
    const int lr   = lane & 15;
    const int grp  = lane >> 4;       // 0..3
    const int kg8  = grp * 8;
    const int rg   = grp * 4;

    const unsigned short* WxTj = WxT + (size_t)j * IN_DIM * IN_DIM;
    const unsigned short* WpTj = WpT + (size_t)j * IN_DIM * 8;

    // staging: thread covers col = i*64 + wv*16 + (lane>>2), chunk (lane&3); LDS linear
    const unsigned short* gst0 = WxTj + (size_t)(wv * 16 + (lane >> 2)) * IN_DIM + (lane & 3) * 8;
    unsigned short* sdst0 = lds + wv * 512;   // wave-uniform; lane*16B implicit

    // A per-lane base: rows rowBase + wr*64 + mt*16 + lr, k = kg8 (+t*32)
    const unsigned short* aBase = inpB + (size_t)(rowBase + wr * 64 + lr) * IN_DIM + kg8;

    // swizzled B-read offsets (u16) within a slot, per nn fragment
    int bro[8];
    #pragma unroll
    for (int nn = 0; nn < 8; ++nn) {
        int col = wc * 128 + nn * 16 + lr;
        bro[nn] = col * PH_BK + (((grp ^ ((col >> 1) & 3)) & 3) << 3);
    }

    f32x4 acc[4][8];
    f32x4 acc2[2] = {};
    s16x8 afA0, afA1, afA2, afA3;
    const unsigned short* gst = gst0;

    #pragma unroll 1
    for (int nt = 0; nt < 2; ++nt) {
        gst = gst0 + (size_t)nt * PH_BNT * IN_DIM;
        #pragma unroll
        for (int mt = 0; mt < 4; ++mt)
            #pragma unroll
            for (int nn = 0; nn < 8; ++nn)
                acc[mt][nn] = f32x4{0.f, 0.f, 0.f, 0.f};

        // prologue FIFO: B(0):4, B(1):4 -> 8 outstanding
        PH_STAGE(0);
        PH_STAGE(1);

        // steady state, per phase t: wait vmcnt(4) (B(t) resident; B(t+1) may fly),
        // LOADA(t) in-phase, STAGE(t+2). The compiler's counted wait before the
        // first MFMA (4 younger = STAGE(t+2)) retires A(t) and force-completes
        // B(t+1) one phase early; B(t+2) stays in flight. Never drains to 0.
        #pragma unroll 1
        for (int t = 0; t < 14; ++t) {
            asm volatile("s_waitcnt vmcnt(4)" ::: "memory");
            __builtin_amdgcn_s_barrier();
            PH_LOADA(t);
            PH_STAGE(t + 2);
            PH_MFMA(t);
        }
        // phase 14: no STAGE; implicit A-wait drains B(15) (needed next anyway)
        asm volatile("s_waitcnt vmcnt(4)" ::: "memory");
        __builtin_amdgcn_s_barrier();
        PH_LOADA(14);
        PH_MFMA(14);
        // phase 15
        __builtin_amdgcn_s_barrier();
        PH_LOADA(15);
        PH_MFMA(15);

        // ---- Hsh (overlays slots) + stage-2 ----
        __builtin_amdgcn_s_barrier();   // all waves done reading slots
        #pragma unroll
        for (int nn = 0; nn < 8; ++nn) {
            int ncol = wc * 128 + nn * 16 + lr;
            float bxv = bx[(size_t)j * IN_DIM + nt * PH_BNT + ncol];
            #pragma unroll
            for (int mt = 0; mt < 4; ++mt)
                #pragma unroll
                for (int v = 0; v < 4; ++v) {
                    float h = acc[mt][nn][v] + bxv;
                    h = h > 0.f ? h : 0.f;
                    lds[(wr * 64 + mt * 16 + rg + v) * PH_HSTR + ncol] = f2bf(h);
                }
        }
        asm volatile("s_waitcnt lgkmcnt(0)" ::: "memory");
        __builtin_amdgcn_s_barrier();
        // stage-2: logits += Hsh @ WpT ; wave wv owns rows wv*32..+32
        #pragma unroll
        for (int k2 = 0; k2 < 8; ++k2) {
            s16x8 b2 = *(const s16x8*)(WpTj + (size_t)(lr & 7) * IN_DIM + nt * PH_BNT + k2 * 32 + kg8);
            #pragma unroll
            for (int m2 = 0; m2 < 2; ++m2) {
                s16x8 a2 = *(const s16x8*)&lds[(wv * 32 + m2 * 16 + lr) * PH_HSTR + k2 * 32 + kg8];
                acc2[m2] = __builtin_amdgcn_mfma_f32_16x16x32_bf16(a2, b2, acc2[m2], 0, 0, 0);
            }
        }
        __builtin_amdgcn_s_barrier();   // Hsh reads done before next nt's staging
    }

    // ---- softmax over 8 cols + parent scale + store ----
    bool valid = lr < 8;
    float bpv = valid ? bp[(size_t)j * 8 + lr] : 0.f;
    #pragma unroll
    for (int m2 = 0; m2 < 2; ++m2) {
        #pragma unroll
        for (int v = 0; v < 4; ++v) {
            float x = acc2[m2][v] + bpv;
            float mx = x;
            for (int d = 1; d < 8; d <<= 1)
                mx = fmaxf(mx, __shfl_xor(mx, d, 64));
            float e = __expf(x - mx);
            float s = e;
            for (int d = 1; d < 8; d <<= 1)
                s += __shfl_xor(s, d, 64);
            float p = e / s;
            int gb = rowBase + wv * 32 + m2 * 16 + rg + v;
            float pv = invert_parent ? (1.f - parent[(size_t)gb * pstride + poff])
                                     : parent[(size_t)gb * pstride + j];
            if (valid)
                outp[(size_t)gb * ostride + j * 8 + lr] = p * pv;
        }
    }
}

// ---------------- fallback (f32-direct) level kernel, used if ws too small ----------------
__global__ __launch_bounds__(256, 2)
void level_ref(const float* __restrict__ inp,
               const float* __restrict__ Wx,
               const float* __restrict__ bx,
               const float* __restrict__ Wp,
               const float* __restrict__ bp,
               const float* __restrict__ parent,
               int pstride, int poff, int invert_parent,
               float* __restrict__ outp, int ostride)
{
    __shared__ __align__(16) unsigned short Ash[128][40];
    __shared__ __align__(16) unsigned short Bsh[128][40];
    __shared__ __align__(16) unsigned short Hsh[128][136];
    __shared__ __align__(16) unsigned short WpSh[8][IN_DIM];

    const int tid  = threadIdx.x;
    const int lane = tid & 63;
    const int wv   = tid >> 6;
    const int j    = blockIdx.y;
    const int rowBase = blockIdx.x * 128;
    const int lr = lane & 15;
    const int kg = (lane >> 4) * 8;
    const int rg = (lane >> 4) * 4;
    const int wm = (wv & 1) * 64;
    const int wn = (wv >> 1) * 64;

    const float* WxJ = Wx + (size_t)j * IN_DIM * IN_DIM;
    const float* WpJ = Wp + (size_t)j * IN_DIM * 8;

    for (int i = tid; i < IN_DIM * 2; i += 256) {
        int k  = i >> 1;
        int w4 = (i & 1) * 4;
        float4 v = *(const float4*)&WpJ[k * 8 + w4];
        WpSh[w4 + 0][k] = f2bf(v.x);
        WpSh[w4 + 1][k] = f2bf(v.y);
        WpSh[w4 + 2][k] = f2bf(v.z);
        WpSh[w4 + 3][k] = f2bf(v.w);
    }

    f32x4 acc2[2] = {};

    for (int nt = 0; nt < 4; ++nt) {
        f32x4 acc[4][4] = {};
        for (int k0 = 0; k0 < IN_DIM; k0 += 32) {
            __syncthreads();
            {
                int kk4 = (tid & 7) * 4;
                int rb  = tid >> 3;
                for (int it = 0; it < 4; ++it) {
                    int r = rb + it * 32;
                    float4 v = *(const float4*)&inp[(size_t)(rowBase + r) * IN_DIM + k0 + kk4];
                    unsigned short* dst = &Ash[r][kk4];
                    dst[0] = f2bf(v.x); dst[1] = f2bf(v.y);
                    dst[2] = f2bf(v.z); dst[3] = f2bf(v.w);
                }
            }
            {
                int n4 = (tid & 31) * 4;
                int kb = tid >> 5;
                for (int it = 0; it < 4; ++it) {
                    int kk = kb + it * 8;
                    float4 v = *(const float4*)&WxJ[(size_t)(k0 + kk) * IN_DIM + nt * 128 + n4];
                    Bsh[n4 + 0][kk] = f2bf(v.x);
                    Bsh[n4 + 1][kk] = f2bf(v.y);
                    Bsh[n4 + 2][kk] = f2bf(v.z);
                    Bsh[n4 + 3][kk] = f2bf(v.w);
                }
            }
            __syncthreads();
            s16x8 af[4], bfr[4];
            for (int mt = 0; mt < 4; ++mt)
                af[mt] = *(const s16x8*)&Ash[wm + mt * 16 + lr][kg];
            for (int nn = 0; nn < 4; ++nn)
                bfr[nn] = *(const s16x8*)&Bsh[wn + nn * 16 + lr][kg];
            for (int mt = 0; mt < 4; ++mt)
                for (int nn = 0; nn < 4; ++nn)
                    acc[mt][nn] = __builtin_amdgcn_mfma_f32_16x16x32_bf16(
                        af[mt], bfr[nn], acc[mt][nn], 0, 0, 0);
        }
        __syncthreads();
        for (int nn = 0; nn < 4; ++nn) {
            int ncol = wn + nn * 16 + lr;
            float bxv = bx[(size_t)j * IN_DIM + nt * 128 + ncol];
            for (int mt = 0; mt < 4; ++mt)
                for (int v = 0; v < 4; ++v) {
                    float h = acc[mt][nn][v] + bxv;
                    h = h > 0.f ? h : 0.f;
                    Hsh[wm + mt * 16 + rg + v][ncol] = f2bf(h);
                }
        }
        __syncthreads();
        {
            s16x8 zero = {};
            for (int k2 = 0; k2 < 128; k2 += 32) {
                s16x8 b2 = (lr < 8) ? *(const s16x8*)&WpSh[lr][nt * 128 + k2 + kg] : zero;
                for (int m2 = 0; m2 < 2; ++m2) {
                    s16x8 a2 = *(const s16x8*)&Hsh[wv * 32 + m2 * 16 + lr][k2 + kg];
                    acc2[m2] = __builtin_amdgcn_mfma_f32_16x16x32_bf16(a2, b2, acc2[m2], 0, 0, 0);
                }
            }
        }
    }

    bool valid = lr < 8;
    float bpv = valid ? bp[(size_t)j * 8 + lr] : 0.f;
    for (int m2 = 0; m2 < 2; ++m2) {
        for (int v = 0; v < 4; ++v) {
            float x = acc2[m2][v] + bpv;
            float mx = x;
            for (int d = 1; d < 8; d <<= 1)
                mx = fmaxf(mx, __shfl_xor(mx, d, 64));
            float e = __expf(x - mx);
            float s = e;
            for (int d = 1; d < 8; d <<= 1)
                s += __shfl_xor(s, d, 64);
            float p = e / s;
            int gb = rowBase + wv * 32 + m2 * 16 + rg + v;
            float pv = invert_parent ? (1.f - parent[(size_t)gb * pstride + poff])
                                     : parent[(size_t)gb * pstride + j];
            if (valid)
                outp[(size_t)gb * ostride + j * 8 + lr] = p * pv;
        }
    }
}

// got_event head
__global__ __launch_bounds__(256)
void head_kernel(const float* __restrict__ inp,
                 const float* __restrict__ We,
                 const float* __restrict__ be,
                 float* __restrict__ out)
{
    int row  = blockIdx.x * 4 + (threadIdx.x >> 6);
    int lane = threadIdx.x & 63;
    const float* ip = inp + (size_t)row * IN_DIM;
    float4 a0 = *(const float4*)&ip[lane * 8];
    float4 a1 = *(const float4*)&ip[lane * 8 + 4];
    float4 w0 = *(const float4*)&We[lane * 8];
    float4 w1 = *(const float4*)&We[lane * 8 + 4];
    float s = a0.x*w0.x + a0.y*w0.y + a0.z*w0.z + a0.w*w0.w
            + a1.x*w1.x + a1.y*w1.y + a1.z*w1.z + a1.w*w1.w;
    for (int d = 1; d < 64; d <<= 1)
        s += __shfl_xor(s, d, 64);
    if (lane == 0) {
        float ge = 1.f / (1.f + __expf(-(s + be[0])));
        float og = 1.f - ge;
        out[(size_t)row * 9 + 8] = og;
        out[(size_t)(NBATCH * 9) + (size_t)row * 65 + 64] = og;
        out[(size_t)(NBATCH * 9 + NBATCH * 65) + (size_t)row * 513 + 512] = og;
    }
}

extern "C" void kernel_launch(void* const* d_in, const int* in_sizes, int n_in,
                              void* d_out, int out_size, void* d_ws, size_t ws_size,
                              hipStream_t stream) {
    const float* inp = (const float*)d_in[0];
    const float* Wx0 = (const float*)d_in[1];
    const float* bx0 = (const float*)d_in[2];
    const float* Wp0 = (const float*)d_in[3];
    const float* bp0 = (const float*)d_in[4];
    const float* Wx1 = (const float*)d_in[5];
    const float* bx1 = (const float*)d_in[6];
    const float* Wp1 = (const float*)d_in[7];
    const float* bp1 = (const float*)d_in[8];
    const float* Wx2 = (const float*)d_in[9];
    const float* bx2 = (const float*)d_in[10];
    const float* Wp2 = (const float*)d_in[11];
    const float* bp2 = (const float*)d_in[12];
    const float* We  = (const float*)d_in[13];
    const float* be  = (const float*)d_in[14];
    float* out = (float*)d_out;

    const size_t OUT1 = (size_t)NBATCH * 9;
    const size_t OUT2 = OUT1 + (size_t)NBATCH * 65;

    const size_t INP_E = (size_t)NBATCH * IN_DIM;
    const size_t WX_E  = (size_t)IN_DIM * IN_DIM;
    const size_t WP_E  = (size_t)IN_DIM * 8;
    const size_t NEED  = 2 * (INP_E + 73 * WX_E + 73 * WP_E);

    head_kernel<<<NBATCH / 4, 256, 0, stream>>>(inp, We, be, out);

    dim3 blk(256);
    bool fast = false;
    if (ws_size >= NEED) {
        hipError_t rc = hipFuncSetAttribute((const void*)level_pipe,
                                            hipFuncAttributeMaxDynamicSharedMemorySize,
                                            PH_LDS_BYTES);
        fast = (rc == hipSuccess);
    }

    if (fast) {
        unsigned short* inpB   = (unsigned short*)d_ws;
        unsigned short* WxTall = inpB + INP_E;
        unsigned short* WpTall = WxTall + 73 * WX_E;

        conv_inp<<<NBATCH * IN_DIM / (256 * 8), 256, 0, stream>>>(inp, inpB);
        conv_wxT<<<dim3(64, 1),  blk, 0, stream>>>(Wx0, WxTall);
        conv_wxT<<<dim3(64, 8),  blk, 0, stream>>>(Wx1, WxTall + 1 * WX_E);
        conv_wxT<<<dim3(64, 64), blk, 0, stream>>>(Wx2, WxTall + 9 * WX_E);
        conv_wpT<<<1,  blk, 0, stream>>>(Wp0, WpTall);
        conv_wpT<<<8,  blk, 0, stream>>>(Wp1, WpTall + 1 * WP_E);
        conv_wpT<<<64, blk, 0, stream>>>(Wp2, WpTall + 9 * WP_E);

        level_pipe<<<dim3(NBATCH / PH_BM, 1), blk, PH_LDS_BYTES, stream>>>(
            inpB, WxTall, bx0, WpTall, bp0, out, 9, 8, 1, out, 9);
        level_pipe<<<dim3(NBATCH / PH_BM, 8), blk, PH_LDS_BYTES, stream>>>(
            inpB, WxTall + 1 * WX_E, bx1, WpTall + 1 * WP_E, bp1,
            out, 9, 0, 0, out + OUT1, 65);
        level_pipe<<<dim3(NBATCH / PH_BM, 64), blk, PH_LDS_BYTES, stream>>>(
            inpB, WxTall + 9 * WX_E, bx2, WpTall + 9 * WP_E, bp2,
            out + OUT1, 65, 0, 0, out + OUT2, 513);
    } else {
        level_ref<<<dim3(NBATCH / 128, 1), blk, 0, stream>>>(
            inp, Wx0, bx0, Wp0, bp0, out, 9, 8, 1, out, 9);
        level_ref<<<dim3(NBATCH / 128, 8), blk, 0, stream>>>(
            inp, Wx1, bx1, Wp1, bp1, out, 9, 0, 0, out + OUT1, 65);
        level_ref<<<dim3(NBATCH / 128, 64), blk, 0, stream>>>(
            inp, Wx2, bx2, Wp2, bp2, out + OUT1, 65, 0, 0, out + OUT2, 513);
    }
}

// Round 9
// 399.072 us; speedup vs baseline: 2.2594x; 1.3947x over previous
//
#include <hip/hip_runtime.h>

#define IN_DIM 512
#define NBATCH 8192
#define NNETS 73

// ---- dp kernel geometry: 128 rows x 256-col half, 4 waves of 64x128, BK=32 ----
#define DP_BM 128
#define DP_BNT 256
#define DP_BK 32
#define DP_SLOT_U16 12288      // A [128][32] = 4096 u16 (8KB) + B [256][32] = 8192 u16 (16KB)
#define DP_B_OFF 4096          // B offset within slot (u16)
#define DP_HSTR 264            // Hsh stride u16
#define DP_LDS_BYTES (3 * DP_SLOT_U16 * 2)   // 73728 B ; Hsh 128*264*2=67584 overlaid

#define SM_STRIDE (NNETS * 8)  // 584 f32 per row

typedef short s16x8 __attribute__((ext_vector_type(8)));
typedef float f32x4 __attribute__((ext_vector_type(4)));

__device__ __forceinline__ unsigned short f2bf(float f) {
    union { float f; unsigned int u; } c;
    c.f = f;
    unsigned int u = c.u;
    u += 0x7fffu + ((u >> 16) & 1u);   // round-to-nearest-even
    return (unsigned short)(u >> 16);
}

__device__ __forceinline__ void gload16(const unsigned short* g, unsigned short* l) {
    __builtin_amdgcn_global_load_lds(
        (const __attribute__((address_space(1))) void*)g,
        (__attribute__((address_space(3))) void*)l,
        16, 0, 0);
}

// ---------------- preprocessing ----------------

// inpB[row][ks*32 + (ct ^ ((row + (row>>2)) & 3))*8 + e] = bf16(inp[row][ks*32 + ct*8 + e])
// (chunk-swizzled within each 32-elem k-slice so the A ds_read is ~conflict-free)
__global__ __launch_bounds__(256)
void conv_inp_swz(const float* __restrict__ in, unsigned short* __restrict__ out) {
    int i = blockIdx.x * 256 + threadIdx.x;    // chunk id (8 elems)
    int row = i >> 6;
    int cin = i & 63;
    int ks = cin >> 2, ct = cin & 3;
    int pos = ct ^ ((row + (row >> 2)) & 3);
    const float* src = in + (size_t)i * 8;
    float4 a = *(const float4*)src;
    float4 b = *(const float4*)(src + 4);
    union { unsigned short u[8]; s16x8 v; } r;
    r.u[0] = f2bf(a.x); r.u[1] = f2bf(a.y); r.u[2] = f2bf(a.z); r.u[3] = f2bf(a.w);
    r.u[4] = f2bf(b.x); r.u[5] = f2bf(b.y); r.u[6] = f2bf(b.z); r.u[7] = f2bf(b.w);
    *(s16x8*)&out[(size_t)row * IN_DIM + ks * 32 + pos * 8] = r.v;
}

// WxT[j][col][k] transposed bf16, chunk ct of each 32-k slice stored at ct ^ ((col>>1)&3)
__global__ __launch_bounds__(256)
void conv_wxT(const float* __restrict__ Wx, unsigned short* __restrict__ WxT) {
    __shared__ unsigned short T[64][80];
    int j  = blockIdx.y;
    int tr = blockIdx.x >> 3;   // k-tile
    int tc = blockIdx.x & 7;    // col-tile
    const float* src = Wx + (size_t)j * IN_DIM * IN_DIM;
    unsigned short* dst = WxT + (size_t)j * IN_DIM * IN_DIM;
    int tid = threadIdx.x;
    int k  = tid >> 2;
    int c0 = (tid & 3) * 16;
    for (int u = 0; u < 16; u += 4) {
        float4 v = *(const float4*)&src[(size_t)(tr * 64 + k) * IN_DIM + tc * 64 + c0 + u];
        T[c0 + u + 0][k] = f2bf(v.x);
        T[c0 + u + 1][k] = f2bf(v.y);
        T[c0 + u + 2][k] = f2bf(v.z);
        T[c0 + u + 3][k] = f2bf(v.w);
    }
    __syncthreads();
    int c   = tid >> 2;
    int k0b = (tid & 3) * 16;
    for (int u = 0; u < 16; u += 8) {
        int kk = k0b + u;
        int ct = (kk >> 3) & 3;
        int pos = (kk & 32) | (((ct ^ ((c >> 1) & 3)) & 3) << 3);
        s16x8 v = *(const s16x8*)&T[c][kk];
        *(s16x8*)&dst[(size_t)(tc * 64 + c) * IN_DIM + tr * 64 + pos] = v;
    }
}

// WpT[j][w][k] = bf16(Wp[j][k][w])
__global__ __launch_bounds__(256)
void conv_wpT(const float* __restrict__ Wp, unsigned short* __restrict__ WpT) {
    int j = blockIdx.x;
    const float* src = Wp + (size_t)j * IN_DIM * 8;
    unsigned short* dst = WpT + (size_t)j * IN_DIM * 8;
    for (int k = threadIdx.x; k < IN_DIM; k += 256)
        for (int w = 0; w < 8; ++w)
            dst[w * IN_DIM + k] = f2bf(src[k * 8 + w]);
}

// ---------------- staging / MFMA macros ----------------

#define DP_STAGE(t) do {                                           \
    unsigned short* sA_ = lds + ((t) % 3) * DP_SLOT_U16 + wv * 1024;  \
    const unsigned short* gA_ = gstA + (size_t)(t) * DP_BK;        \
    gload16(gA_,                         sA_);                     \
    gload16(gA_ + 16 * (size_t)IN_DIM,   sA_ + 512);               \
    unsigned short* sB_ = lds + ((t) % 3) * DP_SLOT_U16 + DP_B_OFF + wv * 512; \
    const unsigned short* gB_ = gstB + (size_t)(t) * DP_BK;        \
    gload16(gB_,                          sB_);                    \
    gload16(gB_ +  64 * (size_t)IN_DIM,   sB_ + 2048);             \
    gload16(gB_ + 128 * (size_t)IN_DIM,   sB_ + 4096);             \
    gload16(gB_ + 192 * (size_t)IN_DIM,   sB_ + 6144);             \
} while (0)

#define DP_MFMA(t) do {                                            \
    const unsigned short* sa_ = lds + ((t) % 3) * DP_SLOT_U16;     \
    const unsigned short* sb_ = sa_ + DP_B_OFF;                    \
    s16x8 af0_ = *(const s16x8*)&sa_[aoff[0]];                     \
    s16x8 af1_ = *(const s16x8*)&sa_[aoff[1]];                     \
    s16x8 af2_ = *(const s16x8*)&sa_[aoff[2]];                     \
    s16x8 af3_ = *(const s16x8*)&sa_[aoff[3]];                     \
    s16x8 bf0_ = *(const s16x8*)&sb_[bro[0]];                      \
    s16x8 bf1_ = *(const s16x8*)&sb_[bro[1]];                      \
    s16x8 bf2_ = *(const s16x8*)&sb_[bro[2]];                      \
    s16x8 bf3_ = *(const s16x8*)&sb_[bro[3]];                      \
    asm volatile("s_waitcnt lgkmcnt(0)" ::: "memory");             \
    __builtin_amdgcn_sched_barrier(0);                             \
    __builtin_amdgcn_s_setprio(1);                                 \
    acc[0][0] = __builtin_amdgcn_mfma_f32_16x16x32_bf16(af0_, bf0_, acc[0][0], 0, 0, 0); \
    acc[1][0] = __builtin_amdgcn_mfma_f32_16x16x32_bf16(af1_, bf0_, acc[1][0], 0, 0, 0); \
    acc[2][0] = __builtin_amdgcn_mfma_f32_16x16x32_bf16(af2_, bf0_, acc[2][0], 0, 0, 0); \
    acc[3][0] = __builtin_amdgcn_mfma_f32_16x16x32_bf16(af3_, bf0_, acc[3][0], 0, 0, 0); \
    acc[0][1] = __builtin_amdgcn_mfma_f32_16x16x32_bf16(af0_, bf1_, acc[0][1], 0, 0, 0); \
    acc[1][1] = __builtin_amdgcn_mfma_f32_16x16x32_bf16(af1_, bf1_, acc[1][1], 0, 0, 0); \
    acc[2][1] = __builtin_amdgcn_mfma_f32_16x16x32_bf16(af2_, bf1_, acc[2][1], 0, 0, 0); \
    acc[3][1] = __builtin_amdgcn_mfma_f32_16x16x32_bf16(af3_, bf1_, acc[3][1], 0, 0, 0); \
    acc[0][2] = __builtin_amdgcn_mfma_f32_16x16x32_bf16(af0_, bf2_, acc[0][2], 0, 0, 0); \
    acc[1][2] = __builtin_amdgcn_mfma_f32_16x16x32_bf16(af1_, bf2_, acc[1][2], 0, 0, 0); \
    acc[2][2] = __builtin_amdgcn_mfma_f32_16x16x32_bf16(af2_, bf2_, acc[2][2], 0, 0, 0); \
    acc[3][2] = __builtin_amdgcn_mfma_f32_16x16x32_bf16(af3_, bf2_, acc[3][2], 0, 0, 0); \
    acc[0][3] = __builtin_amdgcn_mfma_f32_16x16x32_bf16(af0_, bf3_, acc[0][3], 0, 0, 0); \
    acc[1][3] = __builtin_amdgcn_mfma_f32_16x16x32_bf16(af1_, bf3_, acc[1][3], 0, 0, 0); \
    acc[2][3] = __builtin_amdgcn_mfma_f32_16x16x32_bf16(af2_, bf3_, acc[2][3], 0, 0, 0); \
    acc[3][3] = __builtin_amdgcn_mfma_f32_16x16x32_bf16(af3_, bf3_, acc[3][3], 0, 0, 0); \
    __builtin_amdgcn_s_setprio(0);                                 \
    bf0_ = *(const s16x8*)&sb_[bro[4]];                            \
    bf1_ = *(const s16x8*)&sb_[bro[5]];                            \
    bf2_ = *(const s16x8*)&sb_[bro[6]];                            \
    bf3_ = *(const s16x8*)&sb_[bro[7]];                            \
    asm volatile("s_waitcnt lgkmcnt(0)" ::: "memory");             \
    __builtin_amdgcn_sched_barrier(0);                             \
    __builtin_amdgcn_s_setprio(1);                                 \
    acc[0][4] = __builtin_amdgcn_mfma_f32_16x16x32_bf16(af0_, bf0_, acc[0][4], 0, 0, 0); \
    acc[1][4] = __builtin_amdgcn_mfma_f32_16x16x32_bf16(af1_, bf0_, acc[1][4], 0, 0, 0); \
    acc[2][4] = __builtin_amdgcn_mfma_f32_16x16x32_bf16(af2_, bf0_, acc[2][4], 0, 0, 0); \
    acc[3][4] = __builtin_amdgcn_mfma_f32_16x16x32_bf16(af3_, bf0_, acc[3][4], 0, 0, 0); \
    acc[0][5] = __builtin_amdgcn_mfma_f32_16x16x32_bf16(af0_, bf1_, acc[0][5], 0, 0, 0); \
    acc[1][5] = __builtin_amdgcn_mfma_f32_16x16x32_bf16(af1_, bf1_, acc[1][5], 0, 0, 0); \
    acc[2][5] = __builtin_amdgcn_mfma_f32_16x16x32_bf16(af2_, bf1_, acc[2][5], 0, 0, 0); \
    acc[3][5] = __builtin_amdgcn_mfma_f32_16x16x32_bf16(af3_, bf1_, acc[3][5], 0, 0, 0); \
    acc[0][6] = __builtin_amdgcn_mfma_f32_16x16x32_bf16(af0_, bf2_, acc[0][6], 0, 0, 0); \
    acc[1][6] = __builtin_amdgcn_mfma_f32_16x16x32_bf16(af1_, bf2_, acc[1][6], 0, 0, 0); \
    acc[2][6] = __builtin_amdgcn_mfma_f32_16x16x32_bf16(af2_, bf2_, acc[2][6], 0, 0, 0); \
    acc[3][6] = __builtin_amdgcn_mfma_f32_16x16x32_bf16(af3_, bf2_, acc[3][6], 0, 0, 0); \
    acc[0][7] = __builtin_amdgcn_mfma_f32_16x16x32_bf16(af0_, bf3_, acc[0][7], 0, 0, 0); \
    acc[1][7] = __builtin_amdgcn_mfma_f32_16x16x32_bf16(af1_, bf3_, acc[1][7], 0, 0, 0); \
    acc[2][7] = __builtin_amdgcn_mfma_f32_16x16x32_bf16(af2_, bf3_, acc[2][7], 0, 0, 0); \
    acc[3][7] = __builtin_amdgcn_mfma_f32_16x16x32_bf16(af3_, bf3_, acc[3][7], 0, 0, 0); \
    __builtin_amdgcn_s_setprio(0);                                 \
} while (0)

// ---------------- merged GEMM over all 73 nets: sm (softmax, no parent) to ws ----------------
__global__ __launch_bounds__(256, 2)
void gemm_all(const unsigned short* __restrict__ inpB,    // [8192][512] bf16, A-swizzled
              const unsigned short* __restrict__ WxTall,  // [73][col][k] bf16, B-swizzled
              const unsigned short* __restrict__ WpTall,  // [73][8][512] bf16
              const float* __restrict__ bx0, const float* __restrict__ bx1, const float* __restrict__ bx2,
              const float* __restrict__ bp0, const float* __restrict__ bp1, const float* __restrict__ bp2,
              float* __restrict__ smAll)                  // [8192][584] f32
{
    extern __shared__ __align__(16) unsigned short lds[];

    const int tid  = threadIdx.x;
    const int lane = tid & 63;
    const int wv   = tid >> 6;
    const int wr   = wv & 1;          // row half (64 rows)
    const int wc   = wv >> 1;         // col half (128 of 256)
    const int g    = blockIdx.y;      // flattened net 0..72
    const int rowBase = blockIdx.x * DP_BM;
    const int lr   = lane & 15;
    const int grp  = lane >> 4;
    const int kg8  = grp * 8;
    const int rg   = grp * 4;

    const float *bxg, *bpg;
    if (g == 0)      { bxg = bx0;                                bpg = bp0; }
    else if (g < 9)  { bxg = bx1 + (size_t)(g - 1) * IN_DIM;     bpg = bp1 + (size_t)(g - 1) * 8; }
    else             { bxg = bx2 + (size_t)(g - 9) * IN_DIM;     bpg = bp2 + (size_t)(g - 9) * 8; }
    const unsigned short* WxTj = WxTall + (size_t)g * IN_DIM * IN_DIM;
    const unsigned short* WpTj = WpTall + (size_t)g * IN_DIM * 8;

    // staging sources (lane-resolved; LDS dest is linear wave-uniform + lane*16B)
    const unsigned short* gstA = inpB + (size_t)(rowBase + wv * 32 + (lane >> 2)) * IN_DIM + (lane & 3) * 8;
    const unsigned short* gstB0 = WxTj + (size_t)(wv * 16 + (lane >> 2)) * IN_DIM + (lane & 3) * 8;

    // A ds_read offsets: row R, true chunk grp stored at grp ^ ((R + (R>>2)) & 3)
    int aoff[4];
    #pragma unroll
    for (int mt = 0; mt < 4; ++mt) {
        int R = wr * 64 + mt * 16 + lr;
        aoff[mt] = R * DP_BK + (((grp ^ ((R + (R >> 2)) & 3)) & 3) << 3);
    }
    // B ds_read offsets (round-8 proven scheme)
    int bro[8];
    #pragma unroll
    for (int nn = 0; nn < 8; ++nn) {
        int col = wc * 128 + nn * 16 + lr;
        bro[nn] = col * DP_BK + (((grp ^ ((col >> 1) & 3)) & 3) << 3);
    }

    f32x4 acc[4][8];
    f32x4 acc2[2] = {};

    #pragma unroll 1
    for (int nt = 0; nt < 2; ++nt) {
        const unsigned short* gstB = gstB0 + (size_t)nt * DP_BNT * IN_DIM;
        #pragma unroll
        for (int mt = 0; mt < 4; ++mt)
            #pragma unroll
            for (int nn = 0; nn < 8; ++nn)
                acc[mt][nn] = f32x4{0.f, 0.f, 0.f, 0.f};

        // prologue: tiles 0,1 -> 12 loads outstanding
        DP_STAGE(0);
        DP_STAGE(1);

        // per phase: vmcnt(6) retires tile t (6 loads), tile t+1 stays in flight;
        // stage tile t+2 (6 loads) -> back to 12 outstanding. Never drains mid-loop.
        // All MFMA operands come from LDS -> only lgkmcnt waits before MFMA.
        #pragma unroll 1
        for (int t = 0; t < 16; ++t) {
            if (t < 15) { asm volatile("s_waitcnt vmcnt(6)" ::: "memory"); }
            else        { asm volatile("s_waitcnt vmcnt(0)" ::: "memory"); }
            __builtin_amdgcn_s_barrier();
            if (t < 14) DP_STAGE(t + 2);
            DP_MFMA(t);
        }

        // ---- Hsh (overlays slots) + stage-2 ----
        __builtin_amdgcn_s_barrier();   // all waves done reading slots
        #pragma unroll
        for (int nn = 0; nn < 8; ++nn) {
            int ncol = wc * 128 + nn * 16 + lr;
            float bxv = bxg[nt * DP_BNT + ncol];
            #pragma unroll
            for (int mt = 0; mt < 4; ++mt)
                #pragma unroll
                for (int v = 0; v < 4; ++v) {
                    float h = acc[mt][nn][v] + bxv;
                    h = h > 0.f ? h : 0.f;
                    lds[(wr * 64 + mt * 16 + rg + v) * DP_HSTR + ncol] = f2bf(h);
                }
        }
        asm volatile("s_waitcnt lgkmcnt(0)" ::: "memory");
        __builtin_amdgcn_s_barrier();
        #pragma unroll
        for (int k2 = 0; k2 < 8; ++k2) {
            s16x8 b2 = *(const s16x8*)(WpTj + (size_t)(lr & 7) * IN_DIM + nt * DP_BNT + k2 * 32 + kg8);
            #pragma unroll
            for (int m2 = 0; m2 < 2; ++m2) {
                s16x8 a2 = *(const s16x8*)&lds[(wv * 32 + m2 * 16 + lr) * DP_HSTR + k2 * 32 + kg8];
                acc2[m2] = __builtin_amdgcn_mfma_f32_16x16x32_bf16(a2, b2, acc2[m2], 0, 0, 0);
            }
        }
        __builtin_amdgcn_s_barrier();   // Hsh reads done before next nt's staging
    }

    // ---- softmax over 8 cols (no parent) -> smAll ----
    bool valid = lr < 8;
    float bpv = valid ? bpg[lr] : 0.f;
    #pragma unroll
    for (int m2 = 0; m2 < 2; ++m2) {
        #pragma unroll
        for (int v = 0; v < 4; ++v) {
            float x = acc2[m2][v] + bpv;
            float mx = x;
            for (int d = 1; d < 8; d <<= 1)
                mx = fmaxf(mx, __shfl_xor(mx, d, 64));
            float e = __expf(x - mx);
            float s = e;
            for (int d = 1; d < 8; d <<= 1)
                s += __shfl_xor(s, d, 64);
            float p = e / s;
            int gb = rowBase + wv * 32 + m2 * 16 + rg + v;
            if (valid)
                smAll[(size_t)gb * SM_STRIDE + g * 8 + lr] = p;
        }
    }
}

// ---------------- parent-chain epilogues ----------------

__global__ __launch_bounds__(256)
void ep0_kernel(const float* __restrict__ sm, float* __restrict__ out0) {
    int i = blockIdx.x * 256 + threadIdx.x;    // 8192*8
    int b = i >> 3, w = i & 7;
    float ge = 1.f - out0[(size_t)b * 9 + 8];
    out0[(size_t)b * 9 + w] = sm[(size_t)b * SM_STRIDE + w] * ge;
}

__global__ __launch_bounds__(256)
void ep1_kernel(const float* __restrict__ sm, const float* __restrict__ out0,
                float* __restrict__ out1) {
    int i = blockIdx.x * 256 + threadIdx.x;    // 8192*64
    int b = i >> 6, c = i & 63;
    out1[(size_t)b * 65 + c] = sm[(size_t)b * SM_STRIDE + 8 + c] * out0[(size_t)b * 9 + (c >> 3)];
}

__global__ __launch_bounds__(256)
void ep2_kernel(const float* __restrict__ sm, const float* __restrict__ out1,
                float* __restrict__ out2) {
    int i = blockIdx.x * 256 + threadIdx.x;    // 8192*512
    int b = i >> 9, c = i & 511;
    out2[(size_t)b * 513 + c] = sm[(size_t)b * SM_STRIDE + 72 + c] * out1[(size_t)b * 65 + (c >> 3)];
}

// got_event head: writes (1-ge) into last col of all three outputs
__global__ __launch_bounds__(256)
void head_kernel(const float* __restrict__ inp,
                 const float* __restrict__ We,
                 const float* __restrict__ be,
                 float* __restrict__ out)
{
    int row  = blockIdx.x * 4 + (threadIdx.x >> 6);
    int lane = threadIdx.x & 63;
    const float* ip = inp + (size_t)row * IN_DIM;
    float4 a0 = *(const float4*)&ip[lane * 8];
    float4 a1 = *(const float4*)&ip[lane * 8 + 4];
    float4 w0 = *(const float4*)&We[lane * 8];
    float4 w1 = *(const float4*)&We[lane * 8 + 4];
    float s = a0.x*w0.x + a0.y*w0.y + a0.z*w0.z + a0.w*w0.w
            + a1.x*w1.x + a1.y*w1.y + a1.z*w1.z + a1.w*w1.w;
    for (int d = 1; d < 64; d <<= 1)
        s += __shfl_xor(s, d, 64);
    if (lane == 0) {
        float ge = 1.f / (1.f + __expf(-(s + be[0])));
        float og = 1.f - ge;
        out[(size_t)row * 9 + 8] = og;
        out[(size_t)(NBATCH * 9) + (size_t)row * 65 + 64] = og;
        out[(size_t)(NBATCH * 9 + NBATCH * 65) + (size_t)row * 513 + 512] = og;
    }
}

// ---------------- fallback (f32-direct) level kernel, used if ws too small ----------------
__global__ __launch_bounds__(256, 2)
void level_ref(const float* __restrict__ inp,
               const float* __restrict__ Wx,
               const float* __restrict__ bx,
               const float* __restrict__ Wp,
               const float* __restrict__ bp,
               const float* __restrict__ parent,
               int pstride, int poff, int invert_parent,
               float* __restrict__ outp, int ostride)
{
    __shared__ __align__(16) unsigned short Ash[128][40];
    __shared__ __align__(16) unsigned short Bsh[128][40];
    __shared__ __align__(16) unsigned short Hsh[128][136];
    __shared__ __align__(16) unsigned short WpSh[8][IN_DIM];

    const int tid  = threadIdx.x;
    const int lane = tid & 63;
    const int wv   = tid >> 6;
    const int j    = blockIdx.y;
    const int rowBase = blockIdx.x * 128;
    const int lr = lane & 15;
    const int kg = (lane >> 4) * 8;
    const int rg = (lane >> 4) * 4;
    const int wm = (wv & 1) * 64;
    const int wn = (wv >> 1) * 64;

    const float* WxJ = Wx + (size_t)j * IN_DIM * IN_DIM;
    const float* WpJ = Wp + (size_t)j * IN_DIM * 8;

    for (int i = tid; i < IN_DIM * 2; i += 256) {
        int k  = i >> 1;
        int w4 = (i & 1) * 4;
        float4 v = *(const float4*)&WpJ[k * 8 + w4];
        WpSh[w4 + 0][k] = f2bf(v.x);
        WpSh[w4 + 1][k] = f2bf(v.y);
        WpSh[w4 + 2][k] = f2bf(v.z);
        WpSh[w4 + 3][k] = f2bf(v.w);
    }

    f32x4 acc2[2] = {};

    for (int nt = 0; nt < 4; ++nt) {
        f32x4 acc[4][4] = {};
        for (int k0 = 0; k0 < IN_DIM; k0 += 32) {
            __syncthreads();
            {
                int kk4 = (tid & 7) * 4;
                int rb  = tid >> 3;
                for (int it = 0; it < 4; ++it) {
                    int r = rb + it * 32;
                    float4 v = *(const float4*)&inp[(size_t)(rowBase + r) * IN_DIM + k0 + kk4];
                    unsigned short* dst = &Ash[r][kk4];
                    dst[0] = f2bf(v.x); dst[1] = f2bf(v.y);
                    dst[2] = f2bf(v.z); dst[3] = f2bf(v.w);
                }
            }
            {
                int n4 = (tid & 31) * 4;
                int kb = tid >> 5;
                for (int it = 0; it < 4; ++it) {
                    int kk = kb + it * 8;
                    float4 v = *(const float4*)&WxJ[(size_t)(k0 + kk) * IN_DIM + nt * 128 + n4];
                    Bsh[n4 + 0][kk] = f2bf(v.x);
                    Bsh[n4 + 1][kk] = f2bf(v.y);
                    Bsh[n4 + 2][kk] = f2bf(v.z);
                    Bsh[n4 + 3][kk] = f2bf(v.w);
                }
            }
            __syncthreads();
            s16x8 af[4], bfr[4];
            for (int mt = 0; mt < 4; ++mt)
                af[mt] = *(const s16x8*)&Ash[wm + mt * 16 + lr][kg];
            for (int nn = 0; nn < 4; ++nn)
                bfr[nn] = *(const s16x8*)&Bsh[wn + nn * 16 + lr][kg];
            for (int mt = 0; mt < 4; ++mt)
                for (int nn = 0; nn < 4; ++nn)
                    acc[mt][nn] = __builtin_amdgcn_mfma_f32_16x16x32_bf16(
                        af[mt], bfr[nn], acc[mt][nn], 0, 0, 0);
        }
        __syncthreads();
        for (int nn = 0; nn < 4; ++nn) {
            int ncol = wn + nn * 16 + lr;
            float bxv = bx[(size_t)j * IN_DIM + nt * 128 + ncol];
            for (int mt = 0; mt < 4; ++mt)
                for (int v = 0; v < 4; ++v) {
                    float h = acc[mt][nn][v] + bxv;
                    h = h > 0.f ? h : 0.f;
                    Hsh[wm + mt * 16 + rg + v][ncol] = f2bf(h);
                }
        }
        __syncthreads();
        {
            s16x8 zero = {};
            for (int k2 = 0; k2 < 128; k2 += 32) {
                s16x8 b2 = (lr < 8) ? *(const s16x8*)&WpSh[lr][nt * 128 + k2 + kg] : zero;
                for (int m2 = 0; m2 < 2; ++m2) {
                    s16x8 a2 = *(const s16x8*)&Hsh[wv * 32 + m2 * 16 + lr][k2 + kg];
                    acc2[m2] = __builtin_amdgcn_mfma_f32_16x16x32_bf16(a2, b2, acc2[m2], 0, 0, 0);
                }
            }
        }
    }

    bool valid = lr < 8;
    float bpv = valid ? bp[(size_t)j * 8 + lr] : 0.f;
    for (int m2 = 0; m2 < 2; ++m2) {
        for (int v = 0; v < 4; ++v) {
            float x = acc2[m2][v] + bpv;
            float mx = x;
            for (int d = 1; d < 8; d <<= 1)
                mx = fmaxf(mx, __shfl_xor(mx, d, 64));
            float e = __expf(x - mx);
            float s = e;
            for (int d = 1; d < 8; d <<= 1)
                s += __shfl_xor(s, d, 64);
            float p = e / s;
            int gb = rowBase + wv * 32 + m2 * 16 + rg + v;
            float pv = invert_parent ? (1.f - parent[(size_t)gb * pstride + poff])
                                     : parent[(size_t)gb * pstride + j];
            if (valid)
                outp[(size_t)gb * ostride + j * 8 + lr] = p * pv;
        }
    }
}

extern "C" void kernel_launch(void* const* d_in, const int* in_sizes, int n_in,
                              void* d_out, int out_size, void* d_ws, size_t ws_size,
                              hipStream_t stream) {
    const float* inp = (const float*)d_in[0];
    const float* Wx0 = (const float*)d_in[1];
    const float* bx0 = (const float*)d_in[2];
    const float* Wp0 = (const float*)d_in[3];
    const float* bp0 = (const float*)d_in[4];
    const float* Wx1 = (const float*)d_in[5];
    const float* bx1 = (const float*)d_in[6];
    const float* Wp1 = (const float*)d_in[7];
    const float* bp1 = (const float*)d_in[8];
    const float* Wx2 = (const float*)d_in[9];
    const float* bx2 = (const float*)d_in[10];
    const float* Wp2 = (const float*)d_in[11];
    const float* bp2 = (const float*)d_in[12];
    const float* We  = (const float*)d_in[13];
    const float* be  = (const float*)d_in[14];
    float* out = (float*)d_out;

    const size_t OUT1 = (size_t)NBATCH * 9;
    const size_t OUT2 = OUT1 + (size_t)NBATCH * 65;

    const size_t INP_E = (size_t)NBATCH * IN_DIM;
    const size_t WX_E  = (size_t)IN_DIM * IN_DIM;
    const size_t WP_E  = (size_t)IN_DIM * 8;
    const size_t SM_E  = (size_t)NBATCH * SM_STRIDE;
    const size_t NEED  = 2 * (INP_E + NNETS * WX_E + NNETS * WP_E) + 4 * SM_E;

    head_kernel<<<NBATCH / 4, 256, 0, stream>>>(inp, We, be, out);

    dim3 blk(256);
    bool fast = false;
    if (ws_size >= NEED) {
        hipError_t rc = hipFuncSetAttribute((const void*)gemm_all,
                                            hipFuncAttributeMaxDynamicSharedMemorySize,
                                            DP_LDS_BYTES);
        fast = (rc == hipSuccess);
    }

    if (fast) {
        unsigned short* inpB   = (unsigned short*)d_ws;
        unsigned short* WxTall = inpB + INP_E;
        unsigned short* WpTall = WxTall + NNETS * WX_E;
        float* smAll = (float*)(WpTall + NNETS * WP_E);

        conv_inp_swz<<<NBATCH * IN_DIM / (256 * 8), 256, 0, stream>>>(inp, inpB);
        conv_wxT<<<dim3(64, 1),  blk, 0, stream>>>(Wx0, WxTall);
        conv_wxT<<<dim3(64, 8),  blk, 0, stream>>>(Wx1, WxTall + 1 * WX_E);
        conv_wxT<<<dim3(64, 64), blk, 0, stream>>>(Wx2, WxTall + 9 * WX_E);
        conv_wpT<<<1,  blk, 0, stream>>>(Wp0, WpTall);
        conv_wpT<<<8,  blk, 0, stream>>>(Wp1, WpTall + 1 * WP_E);
        conv_wpT<<<64, blk, 0, stream>>>(Wp2, WpTall + 9 * WP_E);

        gemm_all<<<dim3(NBATCH / DP_BM, NNETS), blk, DP_LDS_BYTES, stream>>>(
            inpB, WxTall, WpTall, bx0, bx1, bx2, bp0, bp1, bp2, smAll);

        ep0_kernel<<<NBATCH * 8   / 256, blk, 0, stream>>>(smAll, out);
        ep1_kernel<<<NBATCH * 64  / 256, blk, 0, stream>>>(smAll, out, out + OUT1);
        ep2_kernel<<<NBATCH * 512 / 256, blk, 0, stream>>>(smAll, out + OUT1, out + OUT2);
    } else {
        level_ref<<<dim3(NBATCH / 128, 1), blk, 0, stream>>>(
            inp, Wx0, bx0, Wp0, bp0, out, 9, 8, 1, out, 9);
        level_ref<<<dim3(NBATCH / 128, 8), blk, 0, stream>>>(
            inp, Wx1, bx1, Wp1, bp1, out, 9, 0, 0, out + OUT1, 65);
        level_ref<<<dim3(NBATCH / 128, 64), blk, 0, stream>>>(
            inp, Wx2, bx2, Wp2, bp2, out + OUT1, 65, 0, 0, out + OUT2, 513);
    }
}

// Round 12
// 397.181 us; speedup vs baseline: 2.2702x; 1.0048x over previous
//
#include <hip/hip_runtime.h>

#define IN_DIM 512
#define NBATCH 8192
#define NNETS 73

// ---- dp kernel geometry: 128 rows x 256-col half, 4 waves of 64x128, BK=32 ----
#define DP_BM 128
#define DP_BNT 256
#define DP_BK 32
#define DP_SLOT_U16 12288      // A [128][32] = 4096 u16 (8KB) + B [256][32] = 8192 u16 (16KB)
#define DP_B_OFF 4096          // B offset within slot (u16)
#define DP_HSTR 264            // Hsh stride u16
#define DP_LDS_BYTES (3 * DP_SLOT_U16 * 2)   // 73728 B ; Hsh 128*264*2=67584 overlaid

#define SM_STRIDE (NNETS * 8)  // 584 f32 per row

typedef short s16x8 __attribute__((ext_vector_type(8)));
typedef float f32x4 __attribute__((ext_vector_type(4)));

__device__ __forceinline__ unsigned short f2bf(float f) {
    union { float f; unsigned int u; } c;
    c.f = f;
    unsigned int u = c.u;
    u += 0x7fffu + ((u >> 16) & 1u);   // round-to-nearest-even
    return (unsigned short)(u >> 16);
}

__device__ __forceinline__ void gload16(const unsigned short* g, unsigned short* l) {
    __builtin_amdgcn_global_load_lds(
        (const __attribute__((address_space(1))) void*)g,
        (__attribute__((address_space(3))) void*)l,
        16, 0, 0);
}

// ---------------- preprocessing ----------------

// A-swizzle: chunk ct of each 32-k slice stored at ct ^ ((row + (row>>2)) & 3)
__global__ __launch_bounds__(256)
void conv_inp_swz(const float* __restrict__ in, unsigned short* __restrict__ out) {
    int i = blockIdx.x * 256 + threadIdx.x;    // chunk id (8 elems)
    int row = i >> 6;
    int cin = i & 63;
    int ks = cin >> 2, ct = cin & 3;
    int pos = ct ^ ((row + (row >> 2)) & 3);
    const float* src = in + (size_t)i * 8;
    float4 a = *(const float4*)src;
    float4 b = *(const float4*)(src + 4);
    union { unsigned short u[8]; s16x8 v; } r;
    r.u[0] = f2bf(a.x); r.u[1] = f2bf(a.y); r.u[2] = f2bf(a.z); r.u[3] = f2bf(a.w);
    r.u[4] = f2bf(b.x); r.u[5] = f2bf(b.y); r.u[6] = f2bf(b.z); r.u[7] = f2bf(b.w);
    *(s16x8*)&out[(size_t)row * IN_DIM + ks * 32 + pos * 8] = r.v;
}

// WxT[j][col][k] transposed bf16, chunk ct of each 32-k slice stored at ct ^ ((col>>1)&3)
__global__ __launch_bounds__(256)
void conv_wxT(const float* __restrict__ Wx, unsigned short* __restrict__ WxT) {
    __shared__ unsigned short T[64][80];
    int j  = blockIdx.y;
    int tr = blockIdx.x >> 3;   // k-tile
    int tc = blockIdx.x & 7;    // col-tile
    const float* src = Wx + (size_t)j * IN_DIM * IN_DIM;
    unsigned short* dst = WxT + (size_t)j * IN_DIM * IN_DIM;
    int tid = threadIdx.x;
    int k  = tid >> 2;
    int c0 = (tid & 3) * 16;
    for (int u = 0; u < 16; u += 4) {
        float4 v = *(const float4*)&src[(size_t)(tr * 64 + k) * IN_DIM + tc * 64 + c0 + u];
        T[c0 + u + 0][k] = f2bf(v.x);
        T[c0 + u + 1][k] = f2bf(v.y);
        T[c0 + u + 2][k] = f2bf(v.z);
        T[c0 + u + 3][k] = f2bf(v.w);
    }
    __syncthreads();
    int c   = tid >> 2;
    int k0b = (tid & 3) * 16;
    for (int u = 0; u < 16; u += 8) {
        int kk = k0b + u;
        int ct = (kk >> 3) & 3;
        int pos = (kk & 32) | (((ct ^ ((c >> 1) & 3)) & 3) << 3);
        s16x8 v = *(const s16x8*)&T[c][kk];
        *(s16x8*)&dst[(size_t)(tc * 64 + c) * IN_DIM + tr * 64 + pos] = v;
    }
}

// WpT[j][w][k] = bf16(Wp[j][k][w])
__global__ __launch_bounds__(256)
void conv_wpT(const float* __restrict__ Wp, unsigned short* __restrict__ WpT) {
    int j = blockIdx.x;
    const float* src = Wp + (size_t)j * IN_DIM * 8;
    unsigned short* dst = WpT + (size_t)j * IN_DIM * 8;
    for (int k = threadIdx.x; k < IN_DIM; k += 256)
        for (int w = 0; w < 8; ++w)
            dst[w * IN_DIM + k] = f2bf(src[k * 8 + w]);
}

// ---------------- staging / MFMA macros ----------------

#define DP_STAGE(t) do {                                           \
    unsigned short* sA_ = lds + ((t) % 3) * DP_SLOT_U16 + wv * 1024;  \
    const unsigned short* gA_ = gstA + (size_t)(t) * DP_BK;        \
    gload16(gA_,                         sA_);                     \
    gload16(gA_ + 16 * (size_t)IN_DIM,   sA_ + 512);               \
    unsigned short* sB_ = lds + ((t) % 3) * DP_SLOT_U16 + DP_B_OFF + wv * 512; \
    const unsigned short* gB_ = gstB + (size_t)(t) * DP_BK;        \
    gload16(gB_,                          sB_);                    \
    gload16(gB_ +  64 * (size_t)IN_DIM,   sB_ + 2048);             \
    gload16(gB_ + 128 * (size_t)IN_DIM,   sB_ + 4096);             \
    gload16(gB_ + 192 * (size_t)IN_DIM,   sB_ + 6144);             \
} while (0)

// 12 ds_reads -> single lgkmcnt(0) drain -> 32 MFMAs in one setprio window
#define DP_MFMA(t) do {                                            \
    const unsigned short* sa_ = lds + ((t) % 3) * DP_SLOT_U16;     \
    const unsigned short* sb_ = sa_ + DP_B_OFF;                    \
    s16x8 af0_ = *(const s16x8*)&sa_[aoff[0]];                     \
    s16x8 af1_ = *(const s16x8*)&sa_[aoff[1]];                     \
    s16x8 af2_ = *(const s16x8*)&sa_[aoff[2]];                     \
    s16x8 af3_ = *(const s16x8*)&sa_[aoff[3]];                     \
    s16x8 bf0_ = *(const s16x8*)&sb_[bro[0]];                      \
    s16x8 bf1_ = *(const s16x8*)&sb_[bro[1]];                      \
    s16x8 bf2_ = *(const s16x8*)&sb_[bro[2]];                      \
    s16x8 bf3_ = *(const s16x8*)&sb_[bro[3]];                      \
    s16x8 bf4_ = *(const s16x8*)&sb_[bro[4]];                      \
    s16x8 bf5_ = *(const s16x8*)&sb_[bro[5]];                      \
    s16x8 bf6_ = *(const s16x8*)&sb_[bro[6]];                      \
    s16x8 bf7_ = *(const s16x8*)&sb_[bro[7]];                      \
    asm volatile("s_waitcnt lgkmcnt(0)" ::: "memory");             \
    __builtin_amdgcn_sched_barrier(0);                             \
    __builtin_amdgcn_s_setprio(1);                                 \
    acc[0][0] = __builtin_amdgcn_mfma_f32_16x16x32_bf16(af0_, bf0_, acc[0][0], 0, 0, 0); \
    acc[1][0] = __builtin_amdgcn_mfma_f32_16x16x32_bf16(af1_, bf0_, acc[1][0], 0, 0, 0); \
    acc[2][0] = __builtin_amdgcn_mfma_f32_16x16x32_bf16(af2_, bf0_, acc[2][0], 0, 0, 0); \
    acc[3][0] = __builtin_amdgcn_mfma_f32_16x16x32_bf16(af3_, bf0_, acc[3][0], 0, 0, 0); \
    acc[0][1] = __builtin_amdgcn_mfma_f32_16x16x32_bf16(af0_, bf1_, acc[0][1], 0, 0, 0); \
    acc[1][1] = __builtin_amdgcn_mfma_f32_16x16x32_bf16(af1_, bf1_, acc[1][1], 0, 0, 0); \
    acc[2][1] = __builtin_amdgcn_mfma_f32_16x16x32_bf16(af2_, bf1_, acc[2][1], 0, 0, 0); \
    acc[3][1] = __builtin_amdgcn_mfma_f32_16x16x32_bf16(af3_, bf1_, acc[3][1], 0, 0, 0); \
    acc[0][2] = __builtin_amdgcn_mfma_f32_16x16x32_bf16(af0_, bf2_, acc[0][2], 0, 0, 0); \
    acc[1][2] = __builtin_amdgcn_mfma_f32_16x16x32_bf16(af1_, bf2_, acc[1][2], 0, 0, 0); \
    acc[2][2] = __builtin_amdgcn_mfma_f32_16x16x32_bf16(af2_, bf2_, acc[2][2], 0, 0, 0); \
    acc[3][2] = __builtin_amdgcn_mfma_f32_16x16x32_bf16(af3_, bf2_, acc[3][2], 0, 0, 0); \
    acc[0][3] = __builtin_amdgcn_mfma_f32_16x16x32_bf16(af0_, bf3_, acc[0][3], 0, 0, 0); \
    acc[1][3] = __builtin_amdgcn_mfma_f32_16x16x32_bf16(af1_, bf3_, acc[1][3], 0, 0, 0); \
    acc[2][3] = __builtin_amdgcn_mfma_f32_16x16x32_bf16(af2_, bf3_, acc[2][3], 0, 0, 0); \
    acc[3][3] = __builtin_amdgcn_mfma_f32_16x16x32_bf16(af3_, bf3_, acc[3][3], 0, 0, 0); \
    acc[0][4] = __builtin_amdgcn_mfma_f32_16x16x32_bf16(af0_, bf4_, acc[0][4], 0, 0, 0); \
    acc[1][4] = __builtin_amdgcn_mfma_f32_16x16x32_bf16(af1_, bf4_, acc[1][4], 0, 0, 0); \
    acc[2][4] = __builtin_amdgcn_mfma_f32_16x16x32_bf16(af2_, bf4_, acc[2][4], 0, 0, 0); \
    acc[3][4] = __builtin_amdgcn_mfma_f32_16x16x32_bf16(af3_, bf4_, acc[3][4], 0, 0, 0); \
    acc[0][5] = __builtin_amdgcn_mfma_f32_16x16x32_bf16(af0_, bf5_, acc[0][5], 0, 0, 0); \
    acc[1][5] = __builtin_amdgcn_mfma_f32_16x16x32_bf16(af1_, bf5_, acc[1][5], 0, 0, 0); \
    acc[2][5] = __builtin_amdgcn_mfma_f32_16x16x32_bf16(af2_, bf5_, acc[2][5], 0, 0, 0); \
    acc[3][5] = __builtin_amdgcn_mfma_f32_16x16x32_bf16(af3_, bf5_, acc[3][5], 0, 0, 0); \
    acc[0][6] = __builtin_amdgcn_mfma_f32_16x16x32_bf16(af0_, bf6_, acc[0][6], 0, 0, 0); \
    acc[1][6] = __builtin_amdgcn_mfma_f32_16x16x32_bf16(af1_, bf6_, acc[1][6], 0, 0, 0); \
    acc[2][6] = __builtin_amdgcn_mfma_f32_16x16x32_bf16(af2_, bf6_, acc[2][6], 0, 0, 0); \
    acc[3][6] = __builtin_amdgcn_mfma_f32_16x16x32_bf16(af3_, bf6_, acc[3][6], 0, 0, 0); \
    acc[0][7] = __builtin_amdgcn_mfma_f32_16x16x32_bf16(af0_, bf7_, acc[0][7], 0, 0, 0); \
    acc[1][7] = __builtin_amdgcn_mfma_f32_16x16x32_bf16(af1_, bf7_, acc[1][7], 0, 0, 0); \
    acc[2][7] = __builtin_amdgcn_mfma_f32_16x16x32_bf16(af2_, bf7_, acc[2][7], 0, 0, 0); \
    acc[3][7] = __builtin_amdgcn_mfma_f32_16x16x32_bf16(af3_, bf7_, acc[3][7], 0, 0, 0); \
    __builtin_amdgcn_s_setprio(0);                                 \
} while (0)

// ---------------- merged GEMM over all 73 nets: sm (softmax, no parent) to ws ----------------
__global__ __launch_bounds__(256, 2)
void gemm_all(const unsigned short* __restrict__ inpB,    // [8192][512] bf16, A-swizzled
              const unsigned short* __restrict__ WxTall,  // [73][col][k] bf16, B-swizzled
              const unsigned short* __restrict__ WpTall,  // [73][8][512] bf16
              const float* __restrict__ bx0, const float* __restrict__ bx1, const float* __restrict__ bx2,
              const float* __restrict__ bp0, const float* __restrict__ bp1, const float* __restrict__ bp2,
              float* __restrict__ smAll)                  // [8192][584] f32
{
    extern __shared__ __align__(16) unsigned short lds[];

    const int tid  = threadIdx.x;
    const int lane = tid & 63;
    const int wv   = tid >> 6;
    const int wr   = wv & 1;          // row half (64 rows)
    const int wc   = wv >> 1;         // col half (128 of 256)
    const int g    = blockIdx.y;      // flattened net 0..72
    const int rowBase = blockIdx.x * DP_BM;
    const int lr   = lane & 15;
    const int grp  = lane >> 4;
    const int kg8  = grp * 8;
    const int rg   = grp * 4;

    const float *bxg, *bpg;
    if (g == 0)      { bxg = bx0;                                bpg = bp0; }
    else if (g < 9)  { bxg = bx1 + (size_t)(g - 1) * IN_DIM;     bpg = bp1 + (size_t)(g - 1) * 8; }
    else             { bxg = bx2 + (size_t)(g - 9) * IN_DIM;     bpg = bp2 + (size_t)(g - 9) * 8; }
    const unsigned short* WxTj = WxTall + (size_t)g * IN_DIM * IN_DIM;
    const unsigned short* WpTj = WpTall + (size_t)g * IN_DIM * 8;

    // staging sources (lane-resolved; LDS dest is linear wave-uniform + lane*16B)
    const unsigned short* gstA = inpB + (size_t)(rowBase + wv * 32 + (lane >> 2)) * IN_DIM + (lane & 3) * 8;
    const unsigned short* gstB0 = WxTj + (size_t)(wv * 16 + (lane >> 2)) * IN_DIM + (lane & 3) * 8;

    // A ds_read offsets: row R, true chunk grp stored at grp ^ ((R + (R>>2)) & 3)
    int aoff[4];
    #pragma unroll
    for (int mt = 0; mt < 4; ++mt) {
        int R = wr * 64 + mt * 16 + lr;
        aoff[mt] = R * DP_BK + (((grp ^ ((R + (R >> 2)) & 3)) & 3) << 3);
    }
    // B ds_read offsets
    int bro[8];
    #pragma unroll
    for (int nn = 0; nn < 8; ++nn) {
        int col = wc * 128 + nn * 16 + lr;
        bro[nn] = col * DP_BK + (((grp ^ ((col >> 1) & 3)) & 3) << 3);
    }

    f32x4 acc[4][8];
    f32x4 acc2[2] = {};

    #pragma unroll 1
    for (int nt = 0; nt < 2; ++nt) {
        const unsigned short* gstB = gstB0 + (size_t)nt * DP_BNT * IN_DIM;
        #pragma unroll
        for (int mt = 0; mt < 4; ++mt)
            #pragma unroll
            for (int nn = 0; nn < 8; ++nn)
                acc[mt][nn] = f32x4{0.f, 0.f, 0.f, 0.f};

        // prologue: tiles 0,1 -> 12 loads outstanding
        DP_STAGE(0);
        DP_STAGE(1);

        // per phase: vmcnt(6) retires tile t (6 loads), tile t+1 stays in flight;
        // stage tile t+2 (6 loads) -> back to 12 outstanding. Never drains mid-loop.
        // All MFMA operands come from LDS -> only lgkmcnt waits before MFMA.
        #pragma unroll 1
        for (int t = 0; t < 16; ++t) {
            if (t < 15) { asm volatile("s_waitcnt vmcnt(6)" ::: "memory"); }
            else        { asm volatile("s_waitcnt vmcnt(0)" ::: "memory"); }
            __builtin_amdgcn_s_barrier();
            if (t < 14) DP_STAGE(t + 2);
            DP_MFMA(t);
        }

        // ---- Hsh (overlays slots) + stage-2 ----
        __builtin_amdgcn_s_barrier();   // all waves done reading slots
        #pragma unroll
        for (int nn = 0; nn < 8; ++nn) {
            int ncol = wc * 128 + nn * 16 + lr;
            float bxv = bxg[nt * DP_BNT + ncol];
            #pragma unroll
            for (int mt = 0; mt < 4; ++mt)
                #pragma unroll
                for (int v = 0; v < 4; ++v) {
                    float h = acc[mt][nn][v] + bxv;
                    h = h > 0.f ? h : 0.f;
                    lds[(wr * 64 + mt * 16 + rg + v) * DP_HSTR + ncol] = f2bf(h);
                }
        }
        asm volatile("s_waitcnt lgkmcnt(0)" ::: "memory");
        __builtin_amdgcn_s_barrier();
        #pragma unroll
        for (int k2 = 0; k2 < 8; ++k2) {
            s16x8 b2 = *(const s16x8*)(WpTj + (size_t)(lr & 7) * IN_DIM + nt * DP_BNT + k2 * 32 + kg8);
            #pragma unroll
            for (int m2 = 0; m2 < 2; ++m2) {
                s16x8 a2 = *(const s16x8*)&lds[(wv * 32 + m2 * 16 + lr) * DP_HSTR + k2 * 32 + kg8];
                acc2[m2] = __builtin_amdgcn_mfma_f32_16x16x32_bf16(a2, b2, acc2[m2], 0, 0, 0);
            }
        }
        __builtin_amdgcn_s_barrier();   // Hsh reads done before next nt's staging
    }

    // ---- softmax over 8 cols (no parent) -> smAll ----
    bool valid = lr < 8;
    float bpv = valid ? bpg[lr] : 0.f;
    #pragma unroll
    for (int m2 = 0; m2 < 2; ++m2) {
        #pragma unroll
        for (int v = 0; v < 4; ++v) {
            float x = acc2[m2][v] + bpv;
            float mx = x;
            for (int d = 1; d < 8; d <<= 1)
                mx = fmaxf(mx, __shfl_xor(mx, d, 64));
            float e = __expf(x - mx);
            float s = e;
            for (int d = 1; d < 8; d <<= 1)
                s += __shfl_xor(s, d, 64);
            float p = e / s;
            int gb = rowBase + wv * 32 + m2 * 16 + rg + v;
            if (valid)
                smAll[(size_t)gb * SM_STRIDE + g * 8 + lr] = p;
        }
    }
}

// ---------------- parent-chain epilogues ----------------

__global__ __launch_bounds__(256)
void ep0_kernel(const float* __restrict__ sm, float* __restrict__ out0) {
    int i = blockIdx.x * 256 + threadIdx.x;    // 8192*8
    int b = i >> 3, w = i & 7;
    float ge = 1.f - out0[(size_t)b * 9 + 8];
    out0[(size_t)b * 9 + w] = sm[(size_t)b * SM_STRIDE + w] * ge;
}

__global__ __launch_bounds__(256)
void ep1_kernel(const float* __restrict__ sm, const float* __restrict__ out0,
                float* __restrict__ out1) {
    int i = blockIdx.x * 256 + threadIdx.x;    // 8192*64
    int b = i >> 6, c = i & 63;
    out1[(size_t)b * 65 + c] = sm[(size_t)b * SM_STRIDE + 8 + c] * out0[(size_t)b * 9 + (c >> 3)];
}

__global__ __launch_bounds__(256)
void ep2_kernel(const float* __restrict__ sm, const float* __restrict__ out1,
                float* __restrict__ out2) {
    int i = blockIdx.x * 256 + threadIdx.x;    // 8192*512
    int b = i >> 9, c = i & 511;
    out2[(size_t)b * 513 + c] = sm[(size_t)b * SM_STRIDE + 72 + c] * out1[(size_t)b * 65 + (c >> 3)];
}

// got_event head: writes (1-ge) into last col of all three outputs
__global__ __launch_bounds__(256)
void head_kernel(const float* __restrict__ inp,
                 const float* __restrict__ We,
                 const float* __restrict__ be,
                 float* __restrict__ out)
{
    int row  = blockIdx.x * 4 + (threadIdx.x >> 6);
    int lane = threadIdx.x & 63;
    const float* ip = inp + (size_t)row * IN_DIM;
    float4 a0 = *(const float4*)&ip[lane * 8];
    float4 a1 = *(const float4*)&ip[lane * 8 + 4];
    float4 w0 = *(const float4*)&We[lane * 8];
    float4 w1 = *(const float4*)&We[lane * 8 + 4];
    float s = a0.x*w0.x + a0.y*w0.y + a0.z*w0.z + a0.w*w0.w
            + a1.x*w1.x + a1.y*w1.y + a1.z*w1.z + a1.w*w1.w;
    for (int d = 1; d < 64; d <<= 1)
        s += __shfl_xor(s, d, 64);
    if (lane == 0) {
        float ge = 1.f / (1.f + __expf(-(s + be[0])));
        float og = 1.f - ge;
        out[(size_t)row * 9 + 8] = og;
        out[(size_t)(NBATCH * 9) + (size_t)row * 65 + 64] = og;
        out[(size_t)(NBATCH * 9 + NBATCH * 65) + (size_t)row * 513 + 512] = og;
    }
}

// ---------------- fallback (f32-direct) level kernel, used if ws too small ----------------
__global__ __launch_bounds__(256, 2)
void level_ref(const float* __restrict__ inp,
               const float* __restrict__ Wx,
               const float* __restrict__ bx,
               const float* __restrict__ Wp,
               const float* __restrict__ bp,
               const float* __restrict__ parent,
               int pstride, int poff, int invert_parent,
               float* __restrict__ outp, int ostride)
{
    __shared__ __align__(16) unsigned short Ash[128][40];
    __shared__ __align__(16) unsigned short Bsh[128][40];
    __shared__ __align__(16) unsigned short Hsh[128][136];
    __shared__ __align__(16) unsigned short WpSh[8][IN_DIM];

    const int tid  = threadIdx.x;
    const int lane = tid & 63;
    const int wv   = tid >> 6;
    const int j    = blockIdx.y;
    const int rowBase = blockIdx.x * 128;
    const int lr = lane & 15;
    const int kg = (lane >> 4) * 8;
    const int rg = (lane >> 4) * 4;
    const int wm = (wv & 1) * 64;
    const int wn = (wv >> 1) * 64;

    const float* WxJ = Wx + (size_t)j * IN_DIM * IN_DIM;
    const float* WpJ = Wp + (size_t)j * IN_DIM * 8;

    for (int i = tid; i < IN_DIM * 2; i += 256) {
        int k  = i >> 1;
        int w4 = (i & 1) * 4;
        float4 v = *(const float4*)&WpJ[k * 8 + w4];
        WpSh[w4 + 0][k] = f2bf(v.x);
        WpSh[w4 + 1][k] = f2bf(v.y);
        WpSh[w4 + 2][k] = f2bf(v.z);
        WpSh[w4 + 3][k] = f2bf(v.w);
    }

    f32x4 acc2[2] = {};

    for (int nt = 0; nt < 4; ++nt) {
        f32x4 acc[4][4] = {};
        for (int k0 = 0; k0 < IN_DIM; k0 += 32) {
            __syncthreads();
            {
                int kk4 = (tid & 7) * 4;
                int rb  = tid >> 3;
                for (int it = 0; it < 4; ++it) {
                    int r = rb + it * 32;
                    float4 v = *(const float4*)&inp[(size_t)(rowBase + r) * IN_DIM + k0 + kk4];
                    unsigned short* dst = &Ash[r][kk4];
                    dst[0] = f2bf(v.x); dst[1] = f2bf(v.y);
                    dst[2] = f2bf(v.z); dst[3] = f2bf(v.w);
                }
            }
            {
                int n4 = (tid & 31) * 4;
                int kb = tid >> 5;
                for (int it = 0; it < 4; ++it) {
                    int kk = kb + it * 8;
                    float4 v = *(const float4*)&WxJ[(size_t)(k0 + kk) * IN_DIM + nt * 128 + n4];
                    Bsh[n4 + 0][kk] = f2bf(v.x);
                    Bsh[n4 + 1][kk] = f2bf(v.y);
                    Bsh[n4 + 2][kk] = f2bf(v.z);
                    Bsh[n4 + 3][kk] = f2bf(v.w);
                }
            }
            __syncthreads();
            s16x8 af[4], bfr[4];
            for (int mt = 0; mt < 4; ++mt)
                af[mt] = *(const s16x8*)&Ash[wm + mt * 16 + lr][kg];
            for (int nn = 0; nn < 4; ++nn)
                bfr[nn] = *(const s16x8*)&Bsh[wn + nn * 16 + lr][kg];
            for (int mt = 0; mt < 4; ++mt)
                for (int nn = 0; nn < 4; ++nn)
                    acc[mt][nn] = __builtin_amdgcn_mfma_f32_16x16x32_bf16(
                        af[mt], bfr[nn], acc[mt][nn], 0, 0, 0);
        }
        __syncthreads();
        for (int nn = 0; nn < 4; ++nn) {
            int ncol = wn + nn * 16 + lr;
            float bxv = bx[(size_t)j * IN_DIM + nt * 128 + ncol];
            for (int mt = 0; mt < 4; ++mt)
                for (int v = 0; v < 4; ++v) {
                    float h = acc[mt][nn][v] + bxv;
                    h = h > 0.f ? h : 0.f;
                    Hsh[wm + mt * 16 + rg + v][ncol] = f2bf(h);
                }
        }
        __syncthreads();
        {
            s16x8 zero = {};
            for (int k2 = 0; k2 < 128; k2 += 32) {
                s16x8 b2 = (lr < 8) ? *(const s16x8*)&WpSh[lr][nt * 128 + k2 + kg] : zero;
                for (int m2 = 0; m2 < 2; ++m2) {
                    s16x8 a2 = *(const s16x8*)&Hsh[wv * 32 + m2 * 16 + lr][k2 + kg];
                    acc2[m2] = __builtin_amdgcn_mfma_f32_16x16x32_bf16(a2, b2, acc2[m2], 0, 0, 0);
                }
            }
        }
    }

    bool valid = lr < 8;
    float bpv = valid ? bp[(size_t)j * 8 + lr] : 0.f;
    for (int m2 = 0; m2 < 2; ++m2) {
        for (int v = 0; v < 4; ++v) {
            float x = acc2[m2][v] + bpv;
            float mx = x;
            for (int d = 1; d < 8; d <<= 1)
                mx = fmaxf(mx, __shfl_xor(mx, d, 64));
            float e = __expf(x - mx);
            float s = e;
            for (int d = 1; d < 8; d <<= 1)
                s += __shfl_xor(s, d, 64);
            float p = e / s;
            int gb = rowBase + wv * 32 + m2 * 16 + rg + v;
            float pv = invert_parent ? (1.f - parent[(size_t)gb * pstride + poff])
                                     : parent[(size_t)gb * pstride + j];
            if (valid)
                outp[(size_t)gb * ostride + j * 8 + lr] = p * pv;
        }
    }
}

extern "C" void kernel_launch(void* const* d_in, const int* in_sizes, int n_in,
                              void* d_out, int out_size, void* d_ws, size_t ws_size,
                              hipStream_t stream) {
    const float* inp = (const float*)d_in[0];
    const float* Wx0 = (const float*)d_in[1];
    const float* bx0 = (const float*)d_in[2];
    const float* Wp0 = (const float*)d_in[3];
    const float* bp0 = (const float*)d_in[4];
    const float* Wx1 = (const float*)d_in[5];
    const float* bx1 = (const float*)d_in[6];
    const float* Wp1 = (const float*)d_in[7];
    const float* bp1 = (const float*)d_in[8];
    const float* Wx2 = (const float*)d_in[9];
    const float* bx2 = (const float*)d_in[10];
    const float* Wp2 = (const float*)d_in[11];
    const float* bp2 = (const float*)d_in[12];
    const float* We  = (const float*)d_in[13];
    const float* be  = (const float*)d_in[14];
    float* out = (float*)d_out;

    const size_t OUT1 = (size_t)NBATCH * 9;
    const size_t OUT2 = OUT1 + (size_t)NBATCH * 65;

    const size_t INP_E = (size_t)NBATCH * IN_DIM;
    const size_t WX_E  = (size_t)IN_DIM * IN_DIM;
    const size_t WP_E  = (size_t)IN_DIM * 8;
    const size_t SM_E  = (size_t)NBATCH * SM_STRIDE;
    const size_t NEED  = 2 * (INP_E + NNETS * WX_E + NNETS * WP_E) + 4 * SM_E;

    head_kernel<<<NBATCH / 4, 256, 0, stream>>>(inp, We, be, out);

    dim3 blk(256);
    bool fast = false;
    if (ws_size >= NEED) {
        hipError_t rc = hipFuncSetAttribute((const void*)gemm_all,
                                            hipFuncAttributeMaxDynamicSharedMemorySize,
                                            DP_LDS_BYTES);
        fast = (rc == hipSuccess);
    }

    if (fast) {
        unsigned short* inpB   = (unsigned short*)d_ws;
        unsigned short* WxTall = inpB + INP_E;
        unsigned short* WpTall = WxTall + NNETS * WX_E;
        float* smAll = (float*)(WpTall + NNETS * WP_E);

        conv_inp_swz<<<NBATCH * IN_DIM / (256 * 8), 256, 0, stream>>>(inp, inpB);
        conv_wxT<<<dim3(64, 1),  blk, 0, stream>>>(Wx0, WxTall);
        conv_wxT<<<dim3(64, 8),  blk, 0, stream>>>(Wx1, WxTall + 1 * WX_E);
        conv_wxT<<<dim3(64, 64), blk, 0, stream>>>(Wx2, WxTall + 9 * WX_E);
        conv_wpT<<<1,  blk, 0, stream>>>(Wp0, WpTall);
        conv_wpT<<<8,  blk, 0, stream>>>(Wp1, WpTall + 1 * WP_E);
        conv_wpT<<<64, blk, 0, stream>>>(Wp2, WpTall + 9 * WP_E);

        gemm_all<<<dim3(NBATCH / DP_BM, NNETS), blk, DP_LDS_BYTES, stream>>>(
            inpB, WxTall, WpTall, bx0, bx1, bx2, bp0, bp1, bp2, smAll);

        ep0_kernel<<<NBATCH * 8   / 256, blk, 0, stream>>>(smAll, out);
        ep1_kernel<<<NBATCH * 64  / 256, blk, 0, stream>>>(smAll, out, out + OUT1);
        ep2_kernel<<<NBATCH * 512 / 256, blk, 0, stream>>>(smAll, out + OUT1, out + OUT2);
    } else {
        level_ref<<<dim3(NBATCH / 128, 1), blk, 0, stream>>>(
            inp, Wx0, bx0, Wp0, bp0, out, 9, 8, 1, out, 9);
        level_ref<<<dim3(NBATCH / 128, 8), blk, 0, stream>>>(
            inp, Wx1, bx1, Wp1, bp1, out, 9, 0, 0, out + OUT1, 65);
        level_ref<<<dim3(NBATCH / 128, 64), blk, 0, stream>>>(
            inp, Wx2, bx2, Wp2, bp2, out + OUT1, 65, 0, 0, out + OUT2, 513);
    }
}